// Round 5
// baseline (190.361 us; speedup 1.0000x reference)
//
#include <hip/hip_runtime.h>
#include <math.h>

#define B_    2
#define LQ_   12240
#define C_    256
#define NH_   8
#define NL_   4
#define NP_   4
#define LEN_IN_ 12240
#define MROWS (B_*LQ_)   // 24480
#define MF_   (MROWS/16) // 1530 row fragments
#define KF_   8          // 256/32 k fragments

typedef __attribute__((ext_vector_type(8))) short short8v;   // 8 bf16
typedef __attribute__((ext_vector_type(4))) float f32x4;

__device__ __forceinline__ ushort f2bf_hi(float f) {
    uint u = __builtin_bit_cast(uint, f);
    uint r = (u + 0x7fffu + ((u >> 16) & 1u)) >> 16;
    return (ushort)r;
}
__device__ __forceinline__ float bf2f(ushort h) {
    uint u = ((uint)h) << 16;
    return __builtin_bit_cast(float, u);
}

// packed-B region layout (ushort elements)
#define OFF_VHI 0
#define OFF_VLO 65536
#define OFF_OHI 131072
#define OFF_OLO 196608
#define OFF_AHI 262144
#define OFF_ALO 294912
#define OFF_UHI 327680
#define OFF_ULO 393216

// ---------------------------------------------------------------------------
// Pack weight matrices into MFMA B-fragment order, split hi/lo bf16.
// packed index: (((nf*KF)+kf)*64 + lane)*8 + j   (KF = 8 for K=256)
// ---------------------------------------------------------------------------
__global__ __launch_bounds__(256) void pack_b_kernel(
    const float* __restrict__ Wv, const float* __restrict__ Wo,
    const float* __restrict__ Wa, const float* __restrict__ Wu,
    ushort* __restrict__ out)
{
    int gid = blockIdx.x * 256 + threadIdx.x;
    const float* W; ushort* hi; ushort* lo; int N, rel;
    if (gid < 8192)       { W = Wv; hi = out + OFF_VHI; lo = out + OFF_VLO; N = 256; rel = gid; }
    else if (gid < 16384) { W = Wo; hi = out + OFF_OHI; lo = out + OFF_OLO; N = 256; rel = gid - 8192; }
    else if (gid < 20480) { W = Wa; hi = out + OFF_AHI; lo = out + OFF_ALO; N = 128; rel = gid - 16384; }
    else if (gid < 28672) { W = Wu; hi = out + OFF_UHI; lo = out + OFF_ULO; N = 256; rel = gid - 20480; }
    else return;

    const int lane = rel & 63;
    const int kf   = (rel >> 6) & 7;
    const int nf   = rel >> 9;
    const int row0 = kf * 32 + (lane >> 4) * 8;
    const int col  = nf * 16 + (lane & 15);

    union { ushort u16[8]; uint4 u4; } ch, cl;
#pragma unroll
    for (int j = 0; j < 8; ++j) {
        float x = W[(size_t)(row0 + j) * N + col];
        ushort h = f2bf_hi(x);
        ch.u16[j] = h;
        cl.u16[j] = f2bf_hi(x - bf2f(h));
    }
    *reinterpret_cast<uint4*>(hi + (size_t)rel * 8) = ch.u4;
    *reinterpret_cast<uint4*>(lo + (size_t)rel * 8) = cl.u4;
}

// ---------------------------------------------------------------------------
// Pack activations into MFMA A-fragment order.
//   inflat -> AIH (hi) + AIL (lo);  query -> QH (hi only).
// packed index: (((mf*KF)+kf)*64 + lane)*8 + j
// thread reads A[mf*16 + (lane&15)][kf*32 + (lane>>4)*8 + j], j=0..7
// ---------------------------------------------------------------------------
__global__ __launch_bounds__(256) void pack_a_kernel(
    const float* __restrict__ inflat, const float* __restrict__ query,
    ushort* __restrict__ AIH, ushort* __restrict__ AIL, ushort* __restrict__ QH)
{
    const int NFRAG = MF_ * KF_ * 64;   // 783360
    int gid = blockIdx.x * 256 + threadIdx.x;
    if (gid >= 2 * NFRAG) return;
    const bool isQ = gid >= NFRAG;
    const int rel = isQ ? gid - NFRAG : gid;

    const int lane = rel & 63;
    const int kf   = (rel >> 6) & 7;
    const int mf   = rel >> 9;
    const int row  = mf * 16 + (lane & 15);
    const int k0   = kf * 32 + (lane >> 4) * 8;

    const float* src = (isQ ? query : inflat) + (size_t)row * 256 + k0;
    float4 v0 = reinterpret_cast<const float4*>(src)[0];
    float4 v1 = reinterpret_cast<const float4*>(src)[1];
    float vv[8] = { v0.x, v0.y, v0.z, v0.w, v1.x, v1.y, v1.z, v1.w };

    union { ushort u16[8]; uint4 u4; } hh, ll;
#pragma unroll
    for (int j = 0; j < 8; ++j) {
        ushort h = f2bf_hi(vv[j]);
        hh.u16[j] = h;
        ll.u16[j] = f2bf_hi(vv[j] - bf2f(h));
    }
    if (isQ) {
        *reinterpret_cast<uint4*>(QH + (size_t)rel * 8) = hh.u4;
    } else {
        *reinterpret_cast<uint4*>(AIH + (size_t)rel * 8) = hh.u4;
        *reinterpret_cast<uint4*>(AIL + (size_t)rel * 8) = ll.u4;
    }
}

// ---------------------------------------------------------------------------
// Streaming split-bf16 MFMA GEMM, pre-packed A and B fragments.
//   Block: 256 thr (4 waves). Column block = 64 cols (4 nf frags).
//   B panel (hi [+ lo]) staged ONCE to LDS; then zero barriers:
//   each wave streams row-frags mf: per kf = A uint4 load(s) (global, packed)
//   + 4 (or 8) ds_read_b128 + 4 (or 12) MFMA.  L3 absorbs A re-reads.
// ---------------------------------------------------------------------------
template<int NPASS, bool OUT_BF16>
__global__ __launch_bounds__(256) void gemm_stream_kernel(
    const ushort* __restrict__ Ahi, const ushort* __restrict__ Alo,
    const ushort* __restrict__ Bhi, const ushort* __restrict__ Blo,
    const float* __restrict__ bias, void* __restrict__ Cg,
    int N, int gridRows)
{
    const int t = threadIdx.x, lane = t & 63, wid = t >> 6;
    const int cb = blockIdx.x;
    const int colBase = cb * 64;
    const int PANEL = 4 * KF_ * 64 * 8;   // 16384 ushorts = 32 KB per plane

    __shared__ ushort Bls[(NPASS == 3 ? 2 : 1) * 16384];

    // ---- stage B panel once ----
    {
        const uint4* src = reinterpret_cast<const uint4*>(Bhi) + (size_t)cb * (PANEL / 8);
        uint4* dst = reinterpret_cast<uint4*>(Bls);
        for (int i = t; i < PANEL / 8; i += 256) dst[i] = src[i];
        if (NPASS == 3) {
            const uint4* src2 = reinterpret_cast<const uint4*>(Blo) + (size_t)cb * (PANEL / 8);
            uint4* dst2 = reinterpret_cast<uint4*>(Bls + PANEL);
            for (int i = t; i < PANEL / 8; i += 256) dst2[i] = src2[i];
        }
    }
    __syncthreads();

    const int colLane = lane & 15, rquad = lane >> 4;

    for (int mf = blockIdx.y * 4 + wid; mf < MF_; mf += gridRows * 4) {
        f32x4 acc[4];
#pragma unroll
        for (int f = 0; f < 4; ++f) acc[f] = (f32x4)0.0f;

        const uint4* ah4 = reinterpret_cast<const uint4*>(Ahi) + (size_t)mf * KF_ * 64 + lane;
        const uint4* al4 = reinterpret_cast<const uint4*>(Alo) + (size_t)mf * KF_ * 64 + lane;

#pragma unroll
        for (int kf = 0; kf < KF_; ++kf) {
            uint4 ahv = ah4[kf * 64];
            short8v a = __builtin_bit_cast(short8v, ahv);
            short8v al;
            if (NPASS == 3) al = __builtin_bit_cast(short8v, al4[kf * 64]);
#pragma unroll
            for (int f = 0; f < 4; ++f) {
                uint4 bhv = *reinterpret_cast<const uint4*>(&Bls[((f * KF_ + kf) * 64 + lane) * 8]);
                short8v b = __builtin_bit_cast(short8v, bhv);
                acc[f] = __builtin_amdgcn_mfma_f32_16x16x32_bf16(a, b, acc[f], 0, 0, 0);
                if (NPASS == 3) {
                    uint4 blv = *reinterpret_cast<const uint4*>(&Bls[PANEL + ((f * KF_ + kf) * 64 + lane) * 8]);
                    acc[f] = __builtin_amdgcn_mfma_f32_16x16x32_bf16(
                        a, __builtin_bit_cast(short8v, blv), acc[f], 0, 0, 0);
                    acc[f] = __builtin_amdgcn_mfma_f32_16x16x32_bf16(al, b, acc[f], 0, 0, 0);
                }
            }
        }

        // epilogue (C/D: col = lane&15, row = (lane>>4)*4 + e)
#pragma unroll
        for (int f = 0; f < 4; ++f) {
            int col = colBase + f * 16 + colLane;
            float bv = bias[col];
#pragma unroll
            for (int e = 0; e < 4; ++e) {
                int row = mf * 16 + rquad * 4 + e;
                float r = acc[f][e] + bv;
                if (OUT_BF16)
                    ((ushort*)Cg)[(size_t)row * N + col] = f2bf_hi(r);
                else
                    ((float*)Cg)[(size_t)row * N + col] = r;
            }
        }
    }
}

// ---------------------------------------------------------------------------
// Fused softmax + bilinear sampling on bf16 value.
// Output written directly in packed A-fragment hi/lo form for the out-GEMM.
// ---------------------------------------------------------------------------
__global__ __launch_bounds__(64) void sampler_kernel(
    const ushort* __restrict__ value,  // (B, LEN_IN, 256) bf16
    const float* __restrict__ offs,    // (B*LQ, 256)
    const float* __restrict__ attnw,   // (B*LQ, 128)
    const float* __restrict__ refp,    // (B, LQ, NL, 2)
    ushort* __restrict__ midH, ushort* __restrict__ midL)
{
    const int bq = blockIdx.x;
    const int t  = threadIdx.x;

    __shared__ float s_ref[NL_ * 2];
    __shared__ int   s_addr[144 * 4];
    __shared__ float s_w[144 * 4];

    if (t < NL_ * 2) s_ref[t] = refp[(size_t)bq * (NL_ * 2) + t];
    __syncthreads();

#pragma unroll
    for (int batch = 0; batch < 2; ++batch) {
        const int p  = t + batch * 64;
        const int h  = p >> 4;
        const int lp = p & 15;
        const int l  = lp >> 2;

        float raw = attnw[(size_t)bq * 128 + p];
        float mx = raw;
#pragma unroll
        for (int m = 8; m >= 1; m >>= 1) mx = fmaxf(mx, __shfl_xor(mx, m, 16));
        float e = __expf(raw - mx);
        float sum = e;
#pragma unroll
        for (int m = 8; m >= 1; m >>= 1) sum += __shfl_xor(sum, m, 16);
        const float aw = e / sum;

        const float2 o = reinterpret_cast<const float2*>(offs)[(size_t)bq * 128 + p];
        const float rx = s_ref[l * 2 + 0];
        const float ry = s_ref[l * 2 + 1];

        const int   Wl = 96 >> l;
        const int   st = 12288 - (12288 >> (2 * l));
        const float fW = (float)Wl;

        const float x = fmaf(rx, fW, o.x) - 0.5f;
        const float y = fmaf(ry, fW, o.y) - 0.5f;
        const float x0f = floorf(x), y0f = floorf(y);
        const float fx = x - x0f, fy = y - y0f;
        const int x0 = (int)x0f, y0 = (int)y0f;
        const int x1 = x0 + 1,   y1 = y0 + 1;

        const float vx0 = (x0 >= 0 && x0 < Wl) ? 1.f : 0.f;
        const float vx1 = (x1 >= 0 && x1 < Wl) ? 1.f : 0.f;
        const float vy0 = (y0 >= 0 && y0 < Wl) ? 1.f : 0.f;
        const float vy1 = (y1 >= 0 && y1 < Wl) ? 1.f : 0.f;

        const int xc0 = min(max(x0, 0), Wl - 1);
        const int xc1 = min(max(x1, 0), Wl - 1);
        const int yc0 = min(max(y0, 0), Wl - 1);
        const int yc1 = min(max(y1, 0), Wl - 1);

        const int row0 = st + yc0 * Wl;
        const int row1 = st + yc1 * Wl;
        const int hb   = h << 5;

        const int sidx = (lp * 9 + h) * 4;
        int4 a;
        a.x = ((row0 + xc0) << 8) + hb;
        a.y = ((row0 + xc1) << 8) + hb;
        a.z = ((row1 + xc0) << 8) + hb;
        a.w = ((row1 + xc1) << 8) + hb;
        *reinterpret_cast<int4*>(&s_addr[sidx]) = a;

        float4 w;
        w.x = aw * (1.f - fx) * (1.f - fy) * vx0 * vy0;
        w.y = aw * fx * (1.f - fy) * vx1 * vy0;
        w.z = aw * (1.f - fx) * fy * vx0 * vy1;
        w.w = aw * fx * fy * vx1 * vy1;
        *reinterpret_cast<float4*>(&s_w[sidx]) = w;
    }
    __syncthreads();

    // ---- MAIN: bf16x4 gathers + weighted sum ----
    const int h  = t >> 3;
    const int d4 = (t & 7) * 4;
    const ushort* __restrict__ vb = value + (bq >= LQ_ ? (size_t)LEN_IN_ * 256 : 0) + d4;

    float a0 = 0.f, a1 = 0.f, a2 = 0.f, a3 = 0.f;
#pragma unroll
    for (int pt = 0; pt < 16; ++pt) {
        const int sidx = (pt * 9 + h) * 4;
        const int4   a = *reinterpret_cast<const int4*>(&s_addr[sidx]);
        const float4 w = *reinterpret_cast<const float4*>(&s_w[sidx]);
        ushort4 v00 = *reinterpret_cast<const ushort4*>(vb + a.x);
        ushort4 v01 = *reinterpret_cast<const ushort4*>(vb + a.y);
        ushort4 v10 = *reinterpret_cast<const ushort4*>(vb + a.z);
        ushort4 v11 = *reinterpret_cast<const ushort4*>(vb + a.w);
        a0 = fmaf(w.x, bf2f(v00.x), a0); a1 = fmaf(w.x, bf2f(v00.y), a1);
        a2 = fmaf(w.x, bf2f(v00.z), a2); a3 = fmaf(w.x, bf2f(v00.w), a3);
        a0 = fmaf(w.y, bf2f(v01.x), a0); a1 = fmaf(w.y, bf2f(v01.y), a1);
        a2 = fmaf(w.y, bf2f(v01.z), a2); a3 = fmaf(w.y, bf2f(v01.w), a3);
        a0 = fmaf(w.z, bf2f(v10.x), a0); a1 = fmaf(w.z, bf2f(v10.y), a1);
        a2 = fmaf(w.z, bf2f(v10.z), a2); a3 = fmaf(w.z, bf2f(v10.w), a3);
        a0 = fmaf(w.w, bf2f(v11.x), a0); a1 = fmaf(w.w, bf2f(v11.y), a1);
        a2 = fmaf(w.w, bf2f(v11.z), a2); a3 = fmaf(w.w, bf2f(v11.w), a3);
    }

    // ---- epilogue: split hi/lo, store in packed A-fragment order ----
    ushort h0 = f2bf_hi(a0), h1 = f2bf_hi(a1), h2 = f2bf_hi(a2), h3 = f2bf_hi(a3);
    ushort l0 = f2bf_hi(a0 - bf2f(h0)), l1 = f2bf_hi(a1 - bf2f(h1));
    ushort l2 = f2bf_hi(a2 - bf2f(h2)), l3 = f2bf_hi(a3 - bf2f(h3));

    const int mf = bq >> 4, kf = h;
    const int lanef = (bq & 15) + 16 * (d4 >> 3);
    const int j0 = d4 & 7;
    const size_t base = ((size_t)(mf * KF_ + kf) * 64 + lanef) * 8 + j0;
    *reinterpret_cast<ushort4*>(midH + base) = make_ushort4(h0, h1, h2, h3);
    *reinterpret_cast<ushort4*>(midL + base) = make_ushort4(l0, l1, l2, l3);
}

// ---------------------------------------------------------------------------
extern "C" void kernel_launch(void* const* d_in, const int* in_sizes, int n_in,
                              void* d_out, int out_size, void* d_ws, size_t ws_size,
                              hipStream_t stream)
{
    const float* query  = (const float*)d_in[0];
    const float* refp   = (const float*)d_in[1];
    const float* inflat = (const float*)d_in[2];
    const float* W_off  = (const float*)d_in[5];
    const float* b_off  = (const float*)d_in[6];
    const float* W_attn = (const float*)d_in[7];
    const float* b_attn = (const float*)d_in[8];
    const float* W_val  = (const float*)d_in[9];
    const float* b_val  = (const float*)d_in[10];
    const float* W_out  = (const float*)d_in[11];
    const float* b_out  = (const float*)d_in[12];
    float* out = (float*)d_out;

    const size_t APLANE = (size_t)MF_ * KF_ * 64 * 8;   // 6266880 ushorts

    ushort* AIH   = (ushort*)d_ws;            // also MIDH (aliased after value GEMM)
    ushort* AIL   = AIH + APLANE;             // also MIDL
    ushort* QH    = AIL + APLANE;
    ushort* valbf = QH + APLANE;              // (B, LEN_IN, 256) bf16
    ushort* pack  = valbf + APLANE;
    float*  offsb = (float*)(pack + 458752);  // (B*LQ,256) f32
    float*  attnb = offsb + (size_t)MROWS * C_;

    dim3 blk(256);

    hipLaunchKernelGGL(pack_b_kernel, dim3(112), blk, 0, stream,
                       W_val, W_off, W_attn, W_out, pack);
    hipLaunchKernelGGL(pack_a_kernel, dim3(6120), blk, 0, stream,
                       inflat, query, AIH, AIL, QH);
    hipLaunchKernelGGL((gemm_stream_kernel<3, true>), dim3(4, 128), blk, 0, stream,
                       AIH, AIL, pack + OFF_VHI, pack + OFF_VLO, b_val, valbf, C_, 128);
    hipLaunchKernelGGL((gemm_stream_kernel<1, false>), dim3(4, 128), blk, 0, stream,
                       QH, QH, pack + OFF_OHI, pack + OFF_OLO, b_off, offsb, C_, 128);
    hipLaunchKernelGGL((gemm_stream_kernel<1, false>), dim3(2, 128), blk, 0, stream,
                       QH, QH, pack + OFF_AHI, pack + OFF_ALO, b_attn, attnb, 128, 128);
    hipLaunchKernelGGL(sampler_kernel, dim3(MROWS), dim3(64), 0, stream,
                       valbf, offsb, attnb, refp, AIH, AIL);
    hipLaunchKernelGGL((gemm_stream_kernel<3, false>), dim3(4, 128), blk, 0, stream,
                       AIH, AIL, pack + OFF_UHI, pack + OFF_ULO, b_out, out, C_, 128);
}

// Round 6
// 143.927 us; speedup vs baseline: 1.3226x; 1.3226x over previous
//
#include <hip/hip_runtime.h>
#include <math.h>

#define B_    2
#define LQ_   12240
#define C_    256
#define NH_   8
#define NL_   4
#define NP_   4
#define LEN_IN_ 12240
#define MROWS (B_*LQ_)    // 24480
#define MF_   (MROWS/16)  // 1530 row fragments
#define KF_   8           // 256/32 k fragments
#define APLANE ((size_t)MROWS * C_)   // 6266880 elements

typedef __attribute__((ext_vector_type(8))) short short8v;   // 8 bf16
typedef __attribute__((ext_vector_type(4))) float f32x4;

__device__ __forceinline__ ushort f2bf_hi(float f) {
    uint u = __builtin_bit_cast(uint, f);
    uint r = (u + 0x7fffu + ((u >> 16) & 1u)) >> 16;
    return (ushort)r;
}
__device__ __forceinline__ float bf2f(ushort h) {
    uint u = ((uint)h) << 16;
    return __builtin_bit_cast(float, u);
}

// packed-B region layout (ushort elements)
#define OFF_VHI 0
#define OFF_VLO 65536
#define OFF_OHI 131072
#define OFF_OLO 196608
#define OFF_AHI 262144
#define OFF_ALO 294912
#define OFF_UHI 327680
#define OFF_ULO 393216

// ---------------------------------------------------------------------------
// Pack weight matrices into MFMA B-fragment order, split hi/lo bf16.
// packed index: (((nf*KF)+kf)*64 + lane)*8 + j   (KF = 8 for K=256)
// ---------------------------------------------------------------------------
__global__ __launch_bounds__(256) void pack_b_kernel(
    const float* __restrict__ Wv, const float* __restrict__ Wo,
    const float* __restrict__ Wa, const float* __restrict__ Wu,
    ushort* __restrict__ out)
{
    int gid = blockIdx.x * 256 + threadIdx.x;
    const float* W; ushort* hi; ushort* lo; int N, rel;
    if (gid < 8192)       { W = Wv; hi = out + OFF_VHI; lo = out + OFF_VLO; N = 256; rel = gid; }
    else if (gid < 16384) { W = Wo; hi = out + OFF_OHI; lo = out + OFF_OLO; N = 256; rel = gid - 8192; }
    else if (gid < 20480) { W = Wa; hi = out + OFF_AHI; lo = out + OFF_ALO; N = 128; rel = gid - 16384; }
    else if (gid < 28672) { W = Wu; hi = out + OFF_UHI; lo = out + OFF_ULO; N = 256; rel = gid - 20480; }
    else return;

    const int lane = rel & 63;
    const int kf   = (rel >> 6) & 7;
    const int nf   = rel >> 9;
    const int row0 = kf * 32 + (lane >> 4) * 8;
    const int col  = nf * 16 + (lane & 15);

    union { ushort u16[8]; uint4 u4; } ch, cl;
#pragma unroll
    for (int j = 0; j < 8; ++j) {
        float x = W[(size_t)(row0 + j) * N + col];
        ushort h = f2bf_hi(x);
        ch.u16[j] = h;
        cl.u16[j] = f2bf_hi(x - bf2f(h));
    }
    *reinterpret_cast<uint4*>(hi + (size_t)rel * 8) = ch.u4;
    *reinterpret_cast<uint4*>(lo + (size_t)rel * 8) = cl.u4;
}

// ---------------------------------------------------------------------------
// Convert activations to row-major bf16 planes: inflat -> IH + IL, query -> QH.
// (Row-major bf16 IS A-fragment-ready: a 16x16x32 A-fragment is 8 k-contiguous
//  elements per lane.)
// ---------------------------------------------------------------------------
__global__ __launch_bounds__(256) void pack_a_kernel(
    const float* __restrict__ inflat, const float* __restrict__ query,
    ushort* __restrict__ IH, ushort* __restrict__ IL, ushort* __restrict__ QH)
{
    const int NELEM8 = (int)(APLANE / 8);   // 783360
    int gid = blockIdx.x * 256 + threadIdx.x;
    const bool isQ = gid >= NELEM8;
    const int rel = isQ ? gid - NELEM8 : gid;

    const float* src = (isQ ? query : inflat) + (size_t)rel * 8;
    float4 v0 = reinterpret_cast<const float4*>(src)[0];
    float4 v1 = reinterpret_cast<const float4*>(src)[1];
    float vv[8] = { v0.x, v0.y, v0.z, v0.w, v1.x, v1.y, v1.z, v1.w };

    union { ushort u16[8]; uint4 u4; } hh, ll;
#pragma unroll
    for (int j = 0; j < 8; ++j) {
        ushort h = f2bf_hi(vv[j]);
        hh.u16[j] = h;
        ll.u16[j] = f2bf_hi(vv[j] - bf2f(h));
    }
    if (isQ) {
        *reinterpret_cast<uint4*>(QH + (size_t)rel * 8) = hh.u4;
    } else {
        *reinterpret_cast<uint4*>(IH + (size_t)rel * 8) = hh.u4;
        *reinterpret_cast<uint4*>(IL + (size_t)rel * 8) = ll.u4;
    }
}

// ---------------------------------------------------------------------------
// Streaming split-bf16 MFMA GEMM v2.
//   A: row-major bf16 hi [+ lo] planes (M x 256).
//   B: fragment-packed hi [+ lo] (pack_b), staged once to LDS (one barrier).
//   Block: 256 thr = 4 waves; wave owns 4 mf (64 rows) x 64 cols.
//   Per kf: 4(+4) ds_read_b128 B-regs + 4(+4) A uint4 loads + 16(x3) MFMA.
//   B regs reused across 4 mf -> MFMA-bound, zero per-kf barriers.
// ---------------------------------------------------------------------------
template<int NPASS, bool OUT_BF16>
__global__ __launch_bounds__(256) void gemm_stream_kernel(
    const ushort* __restrict__ Ahi, const ushort* __restrict__ Alo,
    const ushort* __restrict__ Bhi, const ushort* __restrict__ Blo,
    const float* __restrict__ bias, void* __restrict__ Cg, int N)
{
    const int t = threadIdx.x, lane = t & 63, wid = t >> 6;
    const int cb = blockIdx.x;
    const int colBase = cb * 64;
    constexpr int PANEL = 4 * KF_ * 64 * 8;   // 16384 ushorts = 32 KB

    __shared__ ushort Bls[(NPASS == 3 ? 2 : 1) * PANEL];

    {
        const uint4* s = reinterpret_cast<const uint4*>(Bhi) + (size_t)cb * (PANEL / 8);
        uint4* dl = reinterpret_cast<uint4*>(Bls);
        for (int i = t; i < PANEL / 8; i += 256) dl[i] = s[i];
        if (NPASS == 3) {
            const uint4* s2 = reinterpret_cast<const uint4*>(Blo) + (size_t)cb * (PANEL / 8);
            uint4* d2 = reinterpret_cast<uint4*>(Bls + PANEL);
            for (int i = t; i < PANEL / 8; i += 256) d2[i] = s2[i];
        }
    }
    __syncthreads();

    const int mfBase = blockIdx.y * 16 + wid * 4;
    const int frRow = lane & 15, chunk = lane >> 4;

    f32x4 acc[4][4];
#pragma unroll
    for (int mi = 0; mi < 4; ++mi)
#pragma unroll
        for (int f = 0; f < 4; ++f) acc[mi][f] = (f32x4)0.0f;

    for (int kf = 0; kf < KF_; ++kf) {
        uint4 bh[4], bl[4];
#pragma unroll
        for (int f = 0; f < 4; ++f) {
            bh[f] = *reinterpret_cast<const uint4*>(&Bls[((f * KF_ + kf) * 64 + lane) * 8]);
            if (NPASS == 3)
                bl[f] = *reinterpret_cast<const uint4*>(&Bls[PANEL + ((f * KF_ + kf) * 64 + lane) * 8]);
        }
        uint4 ah[4], al[4];
#pragma unroll
        for (int mi = 0; mi < 4; ++mi) {
            int mfv = min(mfBase + mi, MF_ - 1);
            size_t off = ((size_t)(mfv * 16 + frRow)) * 256 + kf * 32 + chunk * 8;
            ah[mi] = *reinterpret_cast<const uint4*>(Ahi + off);
            if (NPASS == 3) al[mi] = *reinterpret_cast<const uint4*>(Alo + off);
        }
#pragma unroll
        for (int mi = 0; mi < 4; ++mi) {
            short8v a = __builtin_bit_cast(short8v, ah[mi]);
#pragma unroll
            for (int f = 0; f < 4; ++f) {
                short8v b = __builtin_bit_cast(short8v, bh[f]);
                acc[mi][f] = __builtin_amdgcn_mfma_f32_16x16x32_bf16(a, b, acc[mi][f], 0, 0, 0);
                if (NPASS == 3) {
                    acc[mi][f] = __builtin_amdgcn_mfma_f32_16x16x32_bf16(
                        a, __builtin_bit_cast(short8v, bl[f]), acc[mi][f], 0, 0, 0);
                    acc[mi][f] = __builtin_amdgcn_mfma_f32_16x16x32_bf16(
                        __builtin_bit_cast(short8v, al[mi]), b, acc[mi][f], 0, 0, 0);
                }
            }
        }
    }

    // epilogue (C/D: col = lane&15, row = (lane>>4)*4 + e)
    const int colLane = lane & 15, rquad = lane >> 4;
#pragma unroll
    for (int mi = 0; mi < 4; ++mi) {
        if (mfBase + mi >= MF_) break;
#pragma unroll
        for (int f = 0; f < 4; ++f) {
            int col = colBase + f * 16 + colLane;
            float bv = bias[col];
#pragma unroll
            for (int e = 0; e < 4; ++e) {
                int row = (mfBase + mi) * 16 + rquad * 4 + e;
                float r = acc[mi][f][e] + bv;
                if (OUT_BF16)
                    ((ushort*)Cg)[(size_t)row * N + col] = f2bf_hi(r);
                else
                    ((float*)Cg)[(size_t)row * N + col] = r;
            }
        }
    }
}

// ---------------------------------------------------------------------------
// Fused softmax + bilinear sampling on bf16 value.
// Output: row-major bf16 hi/lo planes (coalesced ushort4 stores).
// ---------------------------------------------------------------------------
__global__ __launch_bounds__(64) void sampler_kernel(
    const ushort* __restrict__ value,  // (B, LEN_IN, 256) bf16
    const float* __restrict__ offs,    // (B*LQ, 256)
    const float* __restrict__ attnw,   // (B*LQ, 128)
    const float* __restrict__ refp,    // (B, LQ, NL, 2)
    ushort* __restrict__ midH, ushort* __restrict__ midL)
{
    const int bq = blockIdx.x;
    const int t  = threadIdx.x;

    __shared__ float s_ref[NL_ * 2];
    __shared__ int   s_addr[144 * 4];
    __shared__ float s_w[144 * 4];

    if (t < NL_ * 2) s_ref[t] = refp[(size_t)bq * (NL_ * 2) + t];
    __syncthreads();

#pragma unroll
    for (int batch = 0; batch < 2; ++batch) {
        const int p  = t + batch * 64;
        const int h  = p >> 4;
        const int lp = p & 15;
        const int l  = lp >> 2;

        float raw = attnw[(size_t)bq * 128 + p];
        float mx = raw;
#pragma unroll
        for (int m = 8; m >= 1; m >>= 1) mx = fmaxf(mx, __shfl_xor(mx, m, 16));
        float e = __expf(raw - mx);
        float sum = e;
#pragma unroll
        for (int m = 8; m >= 1; m >>= 1) sum += __shfl_xor(sum, m, 16);
        const float aw = e / sum;

        const float2 o = reinterpret_cast<const float2*>(offs)[(size_t)bq * 128 + p];
        const float rx = s_ref[l * 2 + 0];
        const float ry = s_ref[l * 2 + 1];

        const int   Wl = 96 >> l;
        const int   st = 12288 - (12288 >> (2 * l));
        const float fW = (float)Wl;

        const float x = fmaf(rx, fW, o.x) - 0.5f;
        const float y = fmaf(ry, fW, o.y) - 0.5f;
        const float x0f = floorf(x), y0f = floorf(y);
        const float fx = x - x0f, fy = y - y0f;
        const int x0 = (int)x0f, y0 = (int)y0f;
        const int x1 = x0 + 1,   y1 = y0 + 1;

        const float vx0 = (x0 >= 0 && x0 < Wl) ? 1.f : 0.f;
        const float vx1 = (x1 >= 0 && x1 < Wl) ? 1.f : 0.f;
        const float vy0 = (y0 >= 0 && y0 < Wl) ? 1.f : 0.f;
        const float vy1 = (y1 >= 0 && y1 < Wl) ? 1.f : 0.f;

        const int xc0 = min(max(x0, 0), Wl - 1);
        const int xc1 = min(max(x1, 0), Wl - 1);
        const int yc0 = min(max(y0, 0), Wl - 1);
        const int yc1 = min(max(y1, 0), Wl - 1);

        const int row0 = st + yc0 * Wl;
        const int row1 = st + yc1 * Wl;
        const int hb   = h << 5;

        const int sidx = (lp * 9 + h) * 4;
        int4 a;
        a.x = ((row0 + xc0) << 8) + hb;
        a.y = ((row0 + xc1) << 8) + hb;
        a.z = ((row1 + xc0) << 8) + hb;
        a.w = ((row1 + xc1) << 8) + hb;
        *reinterpret_cast<int4*>(&s_addr[sidx]) = a;

        float4 w;
        w.x = aw * (1.f - fx) * (1.f - fy) * vx0 * vy0;
        w.y = aw * fx * (1.f - fy) * vx1 * vy0;
        w.z = aw * (1.f - fx) * fy * vx0 * vy1;
        w.w = aw * fx * fy * vx1 * vy1;
        *reinterpret_cast<float4*>(&s_w[sidx]) = w;
    }
    __syncthreads();

    // ---- MAIN: bf16x4 gathers + weighted sum ----
    const int h  = t >> 3;
    const int d4 = (t & 7) * 4;
    const ushort* __restrict__ vb = value + (bq >= LQ_ ? (size_t)LEN_IN_ * 256 : 0) + d4;

    float a0 = 0.f, a1 = 0.f, a2 = 0.f, a3 = 0.f;
#pragma unroll
    for (int pt = 0; pt < 16; ++pt) {
        const int sidx = (pt * 9 + h) * 4;
        const int4   a = *reinterpret_cast<const int4*>(&s_addr[sidx]);
        const float4 w = *reinterpret_cast<const float4*>(&s_w[sidx]);
        ushort4 v00 = *reinterpret_cast<const ushort4*>(vb + a.x);
        ushort4 v01 = *reinterpret_cast<const ushort4*>(vb + a.y);
        ushort4 v10 = *reinterpret_cast<const ushort4*>(vb + a.z);
        ushort4 v11 = *reinterpret_cast<const ushort4*>(vb + a.w);
        a0 = fmaf(w.x, bf2f(v00.x), a0); a1 = fmaf(w.x, bf2f(v00.y), a1);
        a2 = fmaf(w.x, bf2f(v00.z), a2); a3 = fmaf(w.x, bf2f(v00.w), a3);
        a0 = fmaf(w.y, bf2f(v01.x), a0); a1 = fmaf(w.y, bf2f(v01.y), a1);
        a2 = fmaf(w.y, bf2f(v01.z), a2); a3 = fmaf(w.y, bf2f(v01.w), a3);
        a0 = fmaf(w.z, bf2f(v10.x), a0); a1 = fmaf(w.z, bf2f(v10.y), a1);
        a2 = fmaf(w.z, bf2f(v10.z), a2); a3 = fmaf(w.z, bf2f(v10.w), a3);
        a0 = fmaf(w.w, bf2f(v11.x), a0); a1 = fmaf(w.w, bf2f(v11.y), a1);
        a2 = fmaf(w.w, bf2f(v11.z), a2); a3 = fmaf(w.w, bf2f(v11.w), a3);
    }

    // ---- epilogue: split hi/lo, row-major coalesced stores ----
    ushort h0 = f2bf_hi(a0), h1 = f2bf_hi(a1), h2 = f2bf_hi(a2), h3 = f2bf_hi(a3);
    ushort l0 = f2bf_hi(a0 - bf2f(h0)), l1 = f2bf_hi(a1 - bf2f(h1));
    ushort l2 = f2bf_hi(a2 - bf2f(h2)), l3 = f2bf_hi(a3 - bf2f(h3));

    const size_t base = (size_t)bq * 256 + (h << 5) + d4;
    *reinterpret_cast<ushort4*>(midH + base) = make_ushort4(h0, h1, h2, h3);
    *reinterpret_cast<ushort4*>(midL + base) = make_ushort4(l0, l1, l2, l3);
}

// ---------------------------------------------------------------------------
extern "C" void kernel_launch(void* const* d_in, const int* in_sizes, int n_in,
                              void* d_out, int out_size, void* d_ws, size_t ws_size,
                              hipStream_t stream)
{
    const float* query  = (const float*)d_in[0];
    const float* refp   = (const float*)d_in[1];
    const float* inflat = (const float*)d_in[2];
    const float* W_off  = (const float*)d_in[5];
    const float* b_off  = (const float*)d_in[6];
    const float* W_attn = (const float*)d_in[7];
    const float* b_attn = (const float*)d_in[8];
    const float* W_val  = (const float*)d_in[9];
    const float* b_val  = (const float*)d_in[10];
    const float* W_out  = (const float*)d_in[11];
    const float* b_out  = (const float*)d_in[12];
    float* out = (float*)d_out;

    ushort* IH    = (ushort*)d_ws;            // inflat hi; later aliased as midH
    ushort* IL    = IH + APLANE;              // inflat lo; later aliased as midL
    ushort* QH    = IL + APLANE;              // query hi
    ushort* valbf = QH + APLANE;              // value bf16 (B, LEN_IN, 256)
    ushort* pack  = valbf + APLANE;           // packed B (458752 ushorts)
    float*  offsb = (float*)(pack + 458752);
    float*  attnb = offsb + APLANE;

    dim3 blk(256);

    hipLaunchKernelGGL(pack_b_kernel, dim3(112), blk, 0, stream,
                       W_val, W_off, W_attn, W_out, pack);
    hipLaunchKernelGGL(pack_a_kernel, dim3(6120), blk, 0, stream,
                       inflat, query, IH, IL, QH);
    hipLaunchKernelGGL((gemm_stream_kernel<3, true>), dim3(4, 96), blk, 0, stream,
                       IH, IL, pack + OFF_VHI, pack + OFF_VLO, b_val, valbf, C_);
    hipLaunchKernelGGL((gemm_stream_kernel<1, false>), dim3(4, 96), blk, 0, stream,
                       QH, QH, pack + OFF_OHI, pack + OFF_OLO, b_off, offsb, C_);
    hipLaunchKernelGGL((gemm_stream_kernel<1, false>), dim3(2, 96), blk, 0, stream,
                       QH, QH, pack + OFF_AHI, pack + OFF_ALO, b_attn, attnb, 128);
    hipLaunchKernelGGL(sampler_kernel, dim3(MROWS), dim3(64), 0, stream,
                       valbf, offsb, attnb, refp, IH, IL);
    hipLaunchKernelGGL((gemm_stream_kernel<3, false>), dim3(4, 96), blk, 0, stream,
                       IH, IL, pack + OFF_UHI, pack + OFF_ULO, b_out, out, C_);
}

// Round 7
// 130.311 us; speedup vs baseline: 1.4608x; 1.1045x over previous
//
#include <hip/hip_runtime.h>
#include <math.h>

#define B_    2
#define LQ_   12240
#define C_    256
#define NH_   8
#define NL_   4
#define NP_   4
#define LEN_IN_ 12240
#define MROWS (B_*LQ_)    // 24480
#define MF_   (MROWS/16)  // 1530 row fragments
#define KF_   8           // 256/32 k fragments
#define APLANE ((size_t)MROWS * C_)   // 6266880 elements

typedef __attribute__((ext_vector_type(8))) short short8v;   // 8 bf16
typedef __attribute__((ext_vector_type(4))) float f32x4;

__device__ __forceinline__ ushort f2bf_hi(float f) {
    uint u = __builtin_bit_cast(uint, f);
    uint r = (u + 0x7fffu + ((u >> 16) & 1u)) >> 16;
    return (ushort)r;
}
__device__ __forceinline__ float bf2f(ushort h) {
    uint u = ((uint)h) << 16;
    return __builtin_bit_cast(float, u);
}

// packed-B layout (ushort units), panels of 16384 (=4 nf x KF_ x 64 x 8):
//   [0,65536)        W_val  hi  (nf 0..15)  -> cb 0..3
//   [65536,131072)   W_off  hi  (nf 0..15)  -> cb 4..7
//   [131072,163840)  W_attn hi  (nf 0..7)   -> cb 8..9
//   [163840,229376)  W_out  hi  (nf 0..15)
//   [229376,294912)  W_out  lo
#define OFF_UHI 163840
#define OFF_ULO 229376
#define PACKB_TOTAL 294912

// ---------------------------------------------------------------------------
// Merged pack kernel.
//   blocks [0,6120): activations -> bf16-hi planes (inflat->IH, query->QH)
//   blocks [6120,6232): weights -> B-fragment packed (hi; +lo for W_out)
// B-frag packed index: (((nf*KF)+kf)*64 + lane)*8 + j
// ---------------------------------------------------------------------------
__global__ __launch_bounds__(256) void pack_kernel(
    const float* __restrict__ inflat, const float* __restrict__ query,
    const float* __restrict__ Wv, const float* __restrict__ Wo,
    const float* __restrict__ Wa, const float* __restrict__ Wu,
    ushort* __restrict__ IH, ushort* __restrict__ QH, ushort* __restrict__ packB)
{
    const int NELEM8 = (int)(APLANE / 8);   // 783360
    const int bid = blockIdx.x;
    if (bid < 6120) {
        int gid = bid * 256 + threadIdx.x;      // < 1566720 = 2*NELEM8 exactly
        const bool isQ = gid >= NELEM8;
        const int rel = isQ ? gid - NELEM8 : gid;
        const float* src = (isQ ? query : inflat) + (size_t)rel * 8;
        float4 v0 = reinterpret_cast<const float4*>(src)[0];
        float4 v1 = reinterpret_cast<const float4*>(src)[1];
        float vv[8] = { v0.x, v0.y, v0.z, v0.w, v1.x, v1.y, v1.z, v1.w };
        union { ushort u16[8]; uint4 u4; } hh;
#pragma unroll
        for (int j = 0; j < 8; ++j) hh.u16[j] = f2bf_hi(vv[j]);
        *reinterpret_cast<uint4*>((isQ ? QH : IH) + (size_t)rel * 8) = hh.u4;
        return;
    }

    int gidb = (bid - 6120) * 256 + threadIdx.x;
    if (gidb >= 28672) return;
    const float* W; ushort* hi; ushort* lo = nullptr; int N, rel;
    if (gidb < 8192)       { W = Wv; hi = packB;          N = 256; rel = gidb; }
    else if (gidb < 16384) { W = Wo; hi = packB + 65536;  N = 256; rel = gidb - 8192; }
    else if (gidb < 20480) { W = Wa; hi = packB + 131072; N = 128; rel = gidb - 16384; }
    else { W = Wu; hi = packB + OFF_UHI; lo = packB + OFF_ULO; N = 256; rel = gidb - 20480; }

    const int lane = rel & 63;
    const int kf   = (rel >> 6) & 7;
    const int nf   = rel >> 9;
    const int row0 = kf * 32 + (lane >> 4) * 8;
    const int col  = nf * 16 + (lane & 15);

    union { ushort u16[8]; uint4 u4; } ch, cl;
#pragma unroll
    for (int j = 0; j < 8; ++j) {
        float x = W[(size_t)(row0 + j) * N + col];
        ushort h = f2bf_hi(x);
        ch.u16[j] = h;
        cl.u16[j] = f2bf_hi(x - bf2f(h));
    }
    *reinterpret_cast<uint4*>(hi + (size_t)rel * 8) = ch.u4;
    if (lo) *reinterpret_cast<uint4*>(lo + (size_t)rel * 8) = cl.u4;
}

// ---------------------------------------------------------------------------
// Merged 3-in-1 NPASS1 streaming GEMM (value | offs | attn by column-block).
//   cb 0..3: valbf(bf16,N=256) = IH @ Wv ;  cb 4..7: offsb(f32) = QH @ Wo
//   cb 8..9: attnb(f32,N=128) = QH @ Wa
//   B panel staged once to LDS (32 KB); wave owns 4 mf x 64 cols; no per-kf
//   barriers; B regs reused across 4 mf.
// ---------------------------------------------------------------------------
__global__ __launch_bounds__(256) void gemm3_kernel(
    const ushort* __restrict__ IH, const ushort* __restrict__ QH,
    const ushort* __restrict__ packB,
    const float* __restrict__ b_val, const float* __restrict__ b_off,
    const float* __restrict__ b_attn,
    ushort* __restrict__ valbf, float* __restrict__ offsb, float* __restrict__ attnb)
{
    const int t = threadIdx.x, lane = t & 63, wid = t >> 6;
    const int cb = blockIdx.x;
    constexpr int PANEL = 16384;

    const ushort* Asrc; const float* bias; int N, colBase;
    if (cb < 4)      { Asrc = IH; bias = b_val;  N = 256; colBase = cb * 64; }
    else if (cb < 8) { Asrc = QH; bias = b_off;  N = 256; colBase = (cb - 4) * 64; }
    else             { Asrc = QH; bias = b_attn; N = 128; colBase = (cb - 8) * 64; }

    __shared__ ushort Bls[PANEL];
    {
        const uint4* s = reinterpret_cast<const uint4*>(packB) + (size_t)cb * (PANEL / 8);
        uint4* d = reinterpret_cast<uint4*>(Bls);
        for (int i = t; i < PANEL / 8; i += 256) d[i] = s[i];
    }
    __syncthreads();

    const int mfBase = blockIdx.y * 16 + wid * 4;
    const int frRow = lane & 15, chunk = lane >> 4;

    f32x4 acc[4][4];
#pragma unroll
    for (int mi = 0; mi < 4; ++mi)
#pragma unroll
        for (int f = 0; f < 4; ++f) acc[mi][f] = (f32x4)0.0f;

    for (int kf = 0; kf < KF_; ++kf) {
        uint4 bh[4];
#pragma unroll
        for (int f = 0; f < 4; ++f)
            bh[f] = *reinterpret_cast<const uint4*>(&Bls[((f * KF_ + kf) * 64 + lane) * 8]);
        uint4 ah[4];
#pragma unroll
        for (int mi = 0; mi < 4; ++mi) {
            int mfv = min(mfBase + mi, MF_ - 1);
            size_t off = ((size_t)(mfv * 16 + frRow)) * 256 + kf * 32 + chunk * 8;
            ah[mi] = *reinterpret_cast<const uint4*>(Asrc + off);
        }
#pragma unroll
        for (int mi = 0; mi < 4; ++mi) {
            short8v a = __builtin_bit_cast(short8v, ah[mi]);
#pragma unroll
            for (int f = 0; f < 4; ++f)
                acc[mi][f] = __builtin_amdgcn_mfma_f32_16x16x32_bf16(
                    a, __builtin_bit_cast(short8v, bh[f]), acc[mi][f], 0, 0, 0);
        }
    }

    const int colLane = lane & 15, rquad = lane >> 4;
#pragma unroll
    for (int mi = 0; mi < 4; ++mi) {
        if (mfBase + mi >= MF_) break;
#pragma unroll
        for (int f = 0; f < 4; ++f) {
            int col = colBase + f * 16 + colLane;
            float bv = bias[col];
#pragma unroll
            for (int e = 0; e < 4; ++e) {
                int row = (mfBase + mi) * 16 + rquad * 4 + e;
                float r = acc[mi][f][e] + bv;
                if (cb < 4)      valbf[(size_t)row * 256 + col] = f2bf_hi(r);
                else if (cb < 8) offsb[(size_t)row * 256 + col] = r;
                else             attnb[(size_t)row * 128 + col] = r;
            }
        }
    }
}

// ---------------------------------------------------------------------------
// Out-projection: split-bf16 NPASS3 streaming GEMM (A = midH/midL planes).
// ---------------------------------------------------------------------------
__global__ __launch_bounds__(256) void gemm_out_kernel(
    const ushort* __restrict__ Ahi, const ushort* __restrict__ Alo,
    const ushort* __restrict__ Bhi, const ushort* __restrict__ Blo,
    const float* __restrict__ bias, float* __restrict__ Cg)
{
    const int t = threadIdx.x, lane = t & 63, wid = t >> 6;
    const int cb = blockIdx.x;
    const int colBase = cb * 64;
    constexpr int PANEL = 16384;

    __shared__ ushort Bls[2 * PANEL];
    {
        const uint4* s = reinterpret_cast<const uint4*>(Bhi) + (size_t)cb * (PANEL / 8);
        const uint4* s2 = reinterpret_cast<const uint4*>(Blo) + (size_t)cb * (PANEL / 8);
        uint4* d = reinterpret_cast<uint4*>(Bls);
        uint4* d2 = reinterpret_cast<uint4*>(Bls + PANEL);
        for (int i = t; i < PANEL / 8; i += 256) { d[i] = s[i]; d2[i] = s2[i]; }
    }
    __syncthreads();

    const int mfBase = blockIdx.y * 16 + wid * 4;
    const int frRow = lane & 15, chunk = lane >> 4;

    f32x4 acc[4][4];
#pragma unroll
    for (int mi = 0; mi < 4; ++mi)
#pragma unroll
        for (int f = 0; f < 4; ++f) acc[mi][f] = (f32x4)0.0f;

    for (int kf = 0; kf < KF_; ++kf) {
        uint4 bh[4], bl[4];
#pragma unroll
        for (int f = 0; f < 4; ++f) {
            bh[f] = *reinterpret_cast<const uint4*>(&Bls[((f * KF_ + kf) * 64 + lane) * 8]);
            bl[f] = *reinterpret_cast<const uint4*>(&Bls[PANEL + ((f * KF_ + kf) * 64 + lane) * 8]);
        }
        uint4 ah[4], al[4];
#pragma unroll
        for (int mi = 0; mi < 4; ++mi) {
            int mfv = min(mfBase + mi, MF_ - 1);
            size_t off = ((size_t)(mfv * 16 + frRow)) * 256 + kf * 32 + chunk * 8;
            ah[mi] = *reinterpret_cast<const uint4*>(Ahi + off);
            al[mi] = *reinterpret_cast<const uint4*>(Alo + off);
        }
#pragma unroll
        for (int mi = 0; mi < 4; ++mi) {
            short8v a = __builtin_bit_cast(short8v, ah[mi]);
            short8v alv = __builtin_bit_cast(short8v, al[mi]);
#pragma unroll
            for (int f = 0; f < 4; ++f) {
                short8v b = __builtin_bit_cast(short8v, bh[f]);
                acc[mi][f] = __builtin_amdgcn_mfma_f32_16x16x32_bf16(a, b, acc[mi][f], 0, 0, 0);
                acc[mi][f] = __builtin_amdgcn_mfma_f32_16x16x32_bf16(
                    a, __builtin_bit_cast(short8v, bl[f]), acc[mi][f], 0, 0, 0);
                acc[mi][f] = __builtin_amdgcn_mfma_f32_16x16x32_bf16(alv, b, acc[mi][f], 0, 0, 0);
            }
        }
    }

    const int colLane = lane & 15, rquad = lane >> 4;
#pragma unroll
    for (int mi = 0; mi < 4; ++mi) {
        if (mfBase + mi >= MF_) break;
#pragma unroll
        for (int f = 0; f < 4; ++f) {
            int col = colBase + f * 16 + colLane;
            float bv = bias[col];
#pragma unroll
            for (int e = 0; e < 4; ++e) {
                int row = (mfBase + mi) * 16 + rquad * 4 + e;
                Cg[(size_t)row * 256 + col] = acc[mi][f][e] + bv;
            }
        }
    }
}

// ---------------------------------------------------------------------------
// Fused softmax + bilinear sampling on bf16 value.  128 thr = 2 queries/block
// (raises occupancy past the workgroups/CU cap). Wave w owns query bq*2+w.
// ---------------------------------------------------------------------------
__global__ __launch_bounds__(128) void sampler_kernel(
    const ushort* __restrict__ value,  // (B, LEN_IN, 256) bf16
    const float* __restrict__ offs,    // (B*LQ, 256)
    const float* __restrict__ attnw,   // (B*LQ, 128)
    const float* __restrict__ refp,    // (B, LQ, NL, 2)
    ushort* __restrict__ midH, ushort* __restrict__ midL)
{
    const int t  = threadIdx.x;
    const int qi = t >> 6;             // wave / query-in-block
    const int t6 = t & 63;
    const int q  = blockIdx.x * 2 + qi;

    __shared__ float s_ref[2][8];
    __shared__ int   s_addr[2][576];
    __shared__ float s_w[2][576];

    if (t < 16) s_ref[t >> 3][t & 7] = refp[(size_t)(blockIdx.x * 2 + (t >> 3)) * 8 + (t & 7)];
    __syncthreads();

#pragma unroll
    for (int batch = 0; batch < 2; ++batch) {
        const int p  = t6 + batch * 64;
        const int h  = p >> 4;
        const int lp = p & 15;
        const int l  = lp >> 2;

        float raw = attnw[(size_t)q * 128 + p];
        float mx = raw;
#pragma unroll
        for (int m = 8; m >= 1; m >>= 1) mx = fmaxf(mx, __shfl_xor(mx, m, 16));
        float e = __expf(raw - mx);
        float sum = e;
#pragma unroll
        for (int m = 8; m >= 1; m >>= 1) sum += __shfl_xor(sum, m, 16);
        const float aw = e / sum;

        const float2 o = reinterpret_cast<const float2*>(offs)[(size_t)q * 128 + p];
        const float rx = s_ref[qi][l * 2 + 0];
        const float ry = s_ref[qi][l * 2 + 1];

        const int   Wl = 96 >> l;
        const int   st = 12288 - (12288 >> (2 * l));
        const float fW = (float)Wl;

        const float x = fmaf(rx, fW, o.x) - 0.5f;
        const float y = fmaf(ry, fW, o.y) - 0.5f;
        const float x0f = floorf(x), y0f = floorf(y);
        const float fx = x - x0f, fy = y - y0f;
        const int x0 = (int)x0f, y0 = (int)y0f;
        const int x1 = x0 + 1,   y1 = y0 + 1;

        const float vx0 = (x0 >= 0 && x0 < Wl) ? 1.f : 0.f;
        const float vx1 = (x1 >= 0 && x1 < Wl) ? 1.f : 0.f;
        const float vy0 = (y0 >= 0 && y0 < Wl) ? 1.f : 0.f;
        const float vy1 = (y1 >= 0 && y1 < Wl) ? 1.f : 0.f;

        const int xc0 = min(max(x0, 0), Wl - 1);
        const int xc1 = min(max(x1, 0), Wl - 1);
        const int yc0 = min(max(y0, 0), Wl - 1);
        const int yc1 = min(max(y1, 0), Wl - 1);

        const int row0 = st + yc0 * Wl;
        const int row1 = st + yc1 * Wl;
        const int hb   = h << 5;

        const int sidx = (lp * 9 + h) * 4;
        int4 a;
        a.x = ((row0 + xc0) << 8) + hb;
        a.y = ((row0 + xc1) << 8) + hb;
        a.z = ((row1 + xc0) << 8) + hb;
        a.w = ((row1 + xc1) << 8) + hb;
        *reinterpret_cast<int4*>(&s_addr[qi][sidx]) = a;

        float4 w;
        w.x = aw * (1.f - fx) * (1.f - fy) * vx0 * vy0;
        w.y = aw * fx * (1.f - fy) * vx1 * vy0;
        w.z = aw * (1.f - fx) * fy * vx0 * vy1;
        w.w = aw * fx * fy * vx1 * vy1;
        *reinterpret_cast<float4*>(&s_w[qi][sidx]) = w;
    }
    __syncthreads();

    // ---- MAIN: bf16x4 gathers + weighted sum ----
    const int h  = t6 >> 3;
    const int d4 = (t6 & 7) * 4;
    const ushort* __restrict__ vb = value + (q >= LQ_ ? (size_t)LEN_IN_ * 256 : 0) + d4;

    float a0 = 0.f, a1 = 0.f, a2 = 0.f, a3 = 0.f;
#pragma unroll
    for (int pt = 0; pt < 16; ++pt) {
        const int sidx = (pt * 9 + h) * 4;
        const int4   a = *reinterpret_cast<const int4*>(&s_addr[qi][sidx]);
        const float4 w = *reinterpret_cast<const float4*>(&s_w[qi][sidx]);
        ushort4 v00 = *reinterpret_cast<const ushort4*>(vb + a.x);
        ushort4 v01 = *reinterpret_cast<const ushort4*>(vb + a.y);
        ushort4 v10 = *reinterpret_cast<const ushort4*>(vb + a.z);
        ushort4 v11 = *reinterpret_cast<const ushort4*>(vb + a.w);
        a0 = fmaf(w.x, bf2f(v00.x), a0); a1 = fmaf(w.x, bf2f(v00.y), a1);
        a2 = fmaf(w.x, bf2f(v00.z), a2); a3 = fmaf(w.x, bf2f(v00.w), a3);
        a0 = fmaf(w.y, bf2f(v01.x), a0); a1 = fmaf(w.y, bf2f(v01.y), a1);
        a2 = fmaf(w.y, bf2f(v01.z), a2); a3 = fmaf(w.y, bf2f(v01.w), a3);
        a0 = fmaf(w.z, bf2f(v10.x), a0); a1 = fmaf(w.z, bf2f(v10.y), a1);
        a2 = fmaf(w.z, bf2f(v10.z), a2); a3 = fmaf(w.z, bf2f(v10.w), a3);
        a0 = fmaf(w.w, bf2f(v11.x), a0); a1 = fmaf(w.w, bf2f(v11.y), a1);
        a2 = fmaf(w.w, bf2f(v11.z), a2); a3 = fmaf(w.w, bf2f(v11.w), a3);
    }

    ushort h0 = f2bf_hi(a0), h1 = f2bf_hi(a1), h2 = f2bf_hi(a2), h3 = f2bf_hi(a3);
    ushort l0 = f2bf_hi(a0 - bf2f(h0)), l1 = f2bf_hi(a1 - bf2f(h1));
    ushort l2 = f2bf_hi(a2 - bf2f(h2)), l3 = f2bf_hi(a3 - bf2f(h3));

    const size_t base = (size_t)q * 256 + (h << 5) + d4;
    *reinterpret_cast<ushort4*>(midH + base) = make_ushort4(h0, h1, h2, h3);
    *reinterpret_cast<ushort4*>(midL + base) = make_ushort4(l0, l1, l2, l3);
}

// ---------------------------------------------------------------------------
extern "C" void kernel_launch(void* const* d_in, const int* in_sizes, int n_in,
                              void* d_out, int out_size, void* d_ws, size_t ws_size,
                              hipStream_t stream)
{
    const float* query  = (const float*)d_in[0];
    const float* refp   = (const float*)d_in[1];
    const float* inflat = (const float*)d_in[2];
    const float* W_off  = (const float*)d_in[5];
    const float* b_off  = (const float*)d_in[6];
    const float* W_attn = (const float*)d_in[7];
    const float* b_attn = (const float*)d_in[8];
    const float* W_val  = (const float*)d_in[9];
    const float* b_val  = (const float*)d_in[10];
    const float* W_out  = (const float*)d_in[11];
    const float* b_out  = (const float*)d_in[12];
    float* out = (float*)d_out;

    ushort* IH    = (ushort*)d_ws;            // inflat hi; later aliased as midH
    ushort* QH    = IH + APLANE;              // query hi;  later aliased as midL
    ushort* valbf = QH + APLANE;              // value bf16 (B, LEN_IN, 256)
    ushort* packB = valbf + APLANE;           // packed B (294912 ushorts)
    float*  offsb = (float*)(packB + PACKB_TOTAL);
    float*  attnb = offsb + APLANE;

    dim3 blk(256);

    hipLaunchKernelGGL(pack_kernel, dim3(6232), blk, 0, stream,
                       inflat, query, W_val, W_off, W_attn, W_out, IH, QH, packB);
    hipLaunchKernelGGL(gemm3_kernel, dim3(10, 96), blk, 0, stream,
                       IH, QH, packB, b_val, b_off, b_attn, valbf, offsb, attnb);
    hipLaunchKernelGGL(sampler_kernel, dim3(MROWS / 2), dim3(128), 0, stream,
                       valbf, offsb, attnb, refp, IH /*midH*/, QH /*midL*/);
    hipLaunchKernelGGL(gemm_out_kernel, dim3(4, 96), blk, 0, stream,
                       IH, QH, packB + OFF_UHI, packB + OFF_ULO, b_out, out);
}

// Round 8
// 116.453 us; speedup vs baseline: 1.6347x; 1.1190x over previous
//
#include <hip/hip_runtime.h>
#include <math.h>

#define B_    2
#define LQ_   12240
#define C_    256
#define NH_   8
#define NL_   4
#define NP_   4
#define LEN_IN_ 12240
#define MROWS (B_*LQ_)    // 24480
#define MF_   (MROWS/16)  // 1530 row fragments
#define KF_   8           // 256/32 k fragments
#define APLANE ((size_t)MROWS * C_)   // 6266880 elements

typedef __attribute__((ext_vector_type(8))) short short8v;   // 8 bf16
typedef __attribute__((ext_vector_type(4))) float f32x4;

__device__ __forceinline__ ushort f2bf_hi(float f) {
    uint u = __builtin_bit_cast(uint, f);
    uint r = (u + 0x7fffu + ((u >> 16) & 1u)) >> 16;
    return (ushort)r;
}
__device__ __forceinline__ float bf2f(ushort h) {
    uint u = ((uint)h) << 16;
    return __builtin_bit_cast(float, u);
}

// packed-B layout (ushort units), panels of 16384 (=4 nf x KF_ x 64 x 8):
//   [0,65536)        W_val  hi  (nf 0..15)  -> cb 0..3
//   [65536,131072)   W_off  hi  (nf 0..15)  -> cb 4..7
//   [131072,163840)  W_attn hi  (nf 0..7)   -> cb 8..9
//   [163840,229376)  W_out  hi  (nf 0..15)
//   [229376,294912)  W_out  lo
#define OFF_UHI 163840
#define OFF_ULO 229376
#define PACKB_TOTAL 294912

// ---------------------------------------------------------------------------
// Merged pack kernel.
//   blocks [0,6120): activations -> bf16-hi planes (inflat->IH, query->QH)
//   blocks [6120,6232): weights -> B-fragment packed (hi; +lo for W_out)
// ---------------------------------------------------------------------------
__global__ __launch_bounds__(256) void pack_kernel(
    const float* __restrict__ inflat, const float* __restrict__ query,
    const float* __restrict__ Wv, const float* __restrict__ Wo,
    const float* __restrict__ Wa, const float* __restrict__ Wu,
    ushort* __restrict__ IH, ushort* __restrict__ QH, ushort* __restrict__ packB)
{
    const int NELEM8 = (int)(APLANE / 8);   // 783360
    const int bid = blockIdx.x;
    if (bid < 6120) {
        int gid = bid * 256 + threadIdx.x;
        const bool isQ = gid >= NELEM8;
        const int rel = isQ ? gid - NELEM8 : gid;
        const float* src = (isQ ? query : inflat) + (size_t)rel * 8;
        float4 v0 = reinterpret_cast<const float4*>(src)[0];
        float4 v1 = reinterpret_cast<const float4*>(src)[1];
        float vv[8] = { v0.x, v0.y, v0.z, v0.w, v1.x, v1.y, v1.z, v1.w };
        union { ushort u16[8]; uint4 u4; } hh;
#pragma unroll
        for (int j = 0; j < 8; ++j) hh.u16[j] = f2bf_hi(vv[j]);
        *reinterpret_cast<uint4*>((isQ ? QH : IH) + (size_t)rel * 8) = hh.u4;
        return;
    }

    int gidb = (bid - 6120) * 256 + threadIdx.x;
    if (gidb >= 28672) return;
    const float* W; ushort* hi; ushort* lo = nullptr; int N, rel;
    if (gidb < 8192)       { W = Wv; hi = packB;          N = 256; rel = gidb; }
    else if (gidb < 16384) { W = Wo; hi = packB + 65536;  N = 256; rel = gidb - 8192; }
    else if (gidb < 20480) { W = Wa; hi = packB + 131072; N = 128; rel = gidb - 16384; }
    else { W = Wu; hi = packB + OFF_UHI; lo = packB + OFF_ULO; N = 256; rel = gidb - 20480; }

    const int lane = rel & 63;
    const int kf   = (rel >> 6) & 7;
    const int nf   = rel >> 9;
    const int row0 = kf * 32 + (lane >> 4) * 8;
    const int col  = nf * 16 + (lane & 15);

    union { ushort u16[8]; uint4 u4; } ch, cl;
#pragma unroll
    for (int j = 0; j < 8; ++j) {
        float x = W[(size_t)(row0 + j) * N + col];
        ushort h = f2bf_hi(x);
        ch.u16[j] = h;
        cl.u16[j] = f2bf_hi(x - bf2f(h));
    }
    *reinterpret_cast<uint4*>(hi + (size_t)rel * 8) = ch.u4;
    if (lo) *reinterpret_cast<uint4*>(lo + (size_t)rel * 8) = cl.u4;
}

// ---------------------------------------------------------------------------
// Merged 3-in-1 NPASS1 streaming GEMM (value | offs | attn by column-block).
// ---------------------------------------------------------------------------
__global__ __launch_bounds__(256) void gemm3_kernel(
    const ushort* __restrict__ IH, const ushort* __restrict__ QH,
    const ushort* __restrict__ packB,
    const float* __restrict__ b_val, const float* __restrict__ b_off,
    const float* __restrict__ b_attn,
    ushort* __restrict__ valbf, float* __restrict__ offsb, float* __restrict__ attnb)
{
    const int t = threadIdx.x, lane = t & 63, wid = t >> 6;
    const int cb = blockIdx.x;
    constexpr int PANEL = 16384;

    const ushort* Asrc; const float* bias; int N, colBase;
    if (cb < 4)      { Asrc = IH; bias = b_val;  N = 256; colBase = cb * 64; }
    else if (cb < 8) { Asrc = QH; bias = b_off;  N = 256; colBase = (cb - 4) * 64; }
    else             { Asrc = QH; bias = b_attn; N = 128; colBase = (cb - 8) * 64; }

    __shared__ ushort Bls[PANEL];
    {
        const uint4* s = reinterpret_cast<const uint4*>(packB) + (size_t)cb * (PANEL / 8);
        uint4* d = reinterpret_cast<uint4*>(Bls);
        for (int i = t; i < PANEL / 8; i += 256) d[i] = s[i];
    }
    __syncthreads();

    const int mfBase = blockIdx.y * 16 + wid * 4;
    const int frRow = lane & 15, chunk = lane >> 4;

    f32x4 acc[4][4];
#pragma unroll
    for (int mi = 0; mi < 4; ++mi)
#pragma unroll
        for (int f = 0; f < 4; ++f) acc[mi][f] = (f32x4)0.0f;

    for (int kf = 0; kf < KF_; ++kf) {
        uint4 bh[4];
#pragma unroll
        for (int f = 0; f < 4; ++f)
            bh[f] = *reinterpret_cast<const uint4*>(&Bls[((f * KF_ + kf) * 64 + lane) * 8]);
        uint4 ah[4];
#pragma unroll
        for (int mi = 0; mi < 4; ++mi) {
            int mfv = min(mfBase + mi, MF_ - 1);
            size_t off = ((size_t)(mfv * 16 + frRow)) * 256 + kf * 32 + chunk * 8;
            ah[mi] = *reinterpret_cast<const uint4*>(Asrc + off);
        }
#pragma unroll
        for (int mi = 0; mi < 4; ++mi) {
            short8v a = __builtin_bit_cast(short8v, ah[mi]);
#pragma unroll
            for (int f = 0; f < 4; ++f)
                acc[mi][f] = __builtin_amdgcn_mfma_f32_16x16x32_bf16(
                    a, __builtin_bit_cast(short8v, bh[f]), acc[mi][f], 0, 0, 0);
        }
    }

    const int colLane = lane & 15, rquad = lane >> 4;
#pragma unroll
    for (int mi = 0; mi < 4; ++mi) {
        if (mfBase + mi >= MF_) break;
#pragma unroll
        for (int f = 0; f < 4; ++f) {
            int col = colBase + f * 16 + colLane;
            float bv = bias[col];
#pragma unroll
            for (int e = 0; e < 4; ++e) {
                int row = (mfBase + mi) * 16 + rquad * 4 + e;
                float r = acc[mi][f][e] + bv;
                if (cb < 4)      valbf[(size_t)row * 256 + col] = f2bf_hi(r);
                else if (cb < 8) offsb[(size_t)row * 256 + col] = r;
                else             attnb[(size_t)row * 128 + col] = r;
            }
        }
    }
}

// ---------------------------------------------------------------------------
// Out-projection: split-bf16 NPASS3 streaming GEMM (A = midH/midL planes).
// ---------------------------------------------------------------------------
__global__ __launch_bounds__(256) void gemm_out_kernel(
    const ushort* __restrict__ Ahi, const ushort* __restrict__ Alo,
    const ushort* __restrict__ Bhi, const ushort* __restrict__ Blo,
    const float* __restrict__ bias, float* __restrict__ Cg)
{
    const int t = threadIdx.x, lane = t & 63, wid = t >> 6;
    const int cb = blockIdx.x;
    const int colBase = cb * 64;
    constexpr int PANEL = 16384;

    __shared__ ushort Bls[2 * PANEL];
    {
        const uint4* s = reinterpret_cast<const uint4*>(Bhi) + (size_t)cb * (PANEL / 8);
        const uint4* s2 = reinterpret_cast<const uint4*>(Blo) + (size_t)cb * (PANEL / 8);
        uint4* d = reinterpret_cast<uint4*>(Bls);
        uint4* d2 = reinterpret_cast<uint4*>(Bls + PANEL);
        for (int i = t; i < PANEL / 8; i += 256) { d[i] = s[i]; d2[i] = s2[i]; }
    }
    __syncthreads();

    const int mfBase = blockIdx.y * 16 + wid * 4;
    const int frRow = lane & 15, chunk = lane >> 4;

    f32x4 acc[4][4];
#pragma unroll
    for (int mi = 0; mi < 4; ++mi)
#pragma unroll
        for (int f = 0; f < 4; ++f) acc[mi][f] = (f32x4)0.0f;

    for (int kf = 0; kf < KF_; ++kf) {
        uint4 bh[4], bl[4];
#pragma unroll
        for (int f = 0; f < 4; ++f) {
            bh[f] = *reinterpret_cast<const uint4*>(&Bls[((f * KF_ + kf) * 64 + lane) * 8]);
            bl[f] = *reinterpret_cast<const uint4*>(&Bls[PANEL + ((f * KF_ + kf) * 64 + lane) * 8]);
        }
        uint4 ah[4], al[4];
#pragma unroll
        for (int mi = 0; mi < 4; ++mi) {
            int mfv = min(mfBase + mi, MF_ - 1);
            size_t off = ((size_t)(mfv * 16 + frRow)) * 256 + kf * 32 + chunk * 8;
            ah[mi] = *reinterpret_cast<const uint4*>(Ahi + off);
            al[mi] = *reinterpret_cast<const uint4*>(Alo + off);
        }
#pragma unroll
        for (int mi = 0; mi < 4; ++mi) {
            short8v a = __builtin_bit_cast(short8v, ah[mi]);
            short8v alv = __builtin_bit_cast(short8v, al[mi]);
#pragma unroll
            for (int f = 0; f < 4; ++f) {
                short8v b = __builtin_bit_cast(short8v, bh[f]);
                acc[mi][f] = __builtin_amdgcn_mfma_f32_16x16x32_bf16(a, b, acc[mi][f], 0, 0, 0);
                acc[mi][f] = __builtin_amdgcn_mfma_f32_16x16x32_bf16(
                    a, __builtin_bit_cast(short8v, bl[f]), acc[mi][f], 0, 0, 0);
                acc[mi][f] = __builtin_amdgcn_mfma_f32_16x16x32_bf16(alv, b, acc[mi][f], 0, 0, 0);
            }
        }
    }

    const int colLane = lane & 15, rquad = lane >> 4;
#pragma unroll
    for (int mi = 0; mi < 4; ++mi) {
        if (mfBase + mi >= MF_) break;
#pragma unroll
        for (int f = 0; f < 4; ++f) {
            int col = colBase + f * 16 + colLane;
            float bv = bias[col];
#pragma unroll
            for (int e = 0; e < 4; ++e) {
                int row = (mfBase + mi) * 16 + rquad * 4 + e;
                Cg[(size_t)row * 256 + col] = acc[mi][f][e] + bv;
            }
        }
    }
}

// ---------------------------------------------------------------------------
// Fused softmax + bilinear sampling on bf16 value.  128 thr = 2 queries/block.
// MAIN remapped: lane = c2*32 + h*4 + l2; each lane loads 16B (8 bf16) per
// corner, wave half c2 handles corner-pair {00,01} / {10,11}; final
// shfl_xor(32) reduce merges halves.  bf16 decode via free-hi bitcast trick:
//   f32(u32)   ~= hi-elem (mantissa-tail noise ~2^-8 rel, one-sided)
//   f32(u<<16) == lo-elem exactly
// ---------------------------------------------------------------------------
__global__ __launch_bounds__(128) void sampler_kernel(
    const ushort* __restrict__ value,  // (B, LEN_IN, 256) bf16
    const float* __restrict__ offs,    // (B*LQ, 256)
    const float* __restrict__ attnw,   // (B*LQ, 128)
    const float* __restrict__ refp,    // (B, LQ, NL, 2)
    ushort* __restrict__ midH, ushort* __restrict__ midL)
{
    const int t  = threadIdx.x;
    const int qi = t >> 6;             // wave / query-in-block
    const int t6 = t & 63;
    const int q  = blockIdx.x * 2 + qi;

    __shared__ float s_ref[2][8];
    __shared__ int   s_addr[2][576];
    __shared__ float s_w[2][576];

    if (t < 16) s_ref[t >> 3][t & 7] = refp[(size_t)(blockIdx.x * 2 + (t >> 3)) * 8 + (t & 7)];
    __syncthreads();

#pragma unroll
    for (int batch = 0; batch < 2; ++batch) {
        const int p  = t6 + batch * 64;
        const int h  = p >> 4;
        const int lp = p & 15;
        const int l  = lp >> 2;

        float raw = attnw[(size_t)q * 128 + p];
        float mx = raw;
#pragma unroll
        for (int m = 8; m >= 1; m >>= 1) mx = fmaxf(mx, __shfl_xor(mx, m, 16));
        float e = __expf(raw - mx);
        float sum = e;
#pragma unroll
        for (int m = 8; m >= 1; m >>= 1) sum += __shfl_xor(sum, m, 16);
        const float aw = e / sum;

        const float2 o = reinterpret_cast<const float2*>(offs)[(size_t)q * 128 + p];
        const float rx = s_ref[qi][l * 2 + 0];
        const float ry = s_ref[qi][l * 2 + 1];

        const int   Wl = 96 >> l;
        const int   st = 12288 - (12288 >> (2 * l));
        const float fW = (float)Wl;

        const float x = fmaf(rx, fW, o.x) - 0.5f;
        const float y = fmaf(ry, fW, o.y) - 0.5f;
        const float x0f = floorf(x), y0f = floorf(y);
        const float fx = x - x0f, fy = y - y0f;
        const int x0 = (int)x0f, y0 = (int)y0f;
        const int x1 = x0 + 1,   y1 = y0 + 1;

        const float vx0 = (x0 >= 0 && x0 < Wl) ? 1.f : 0.f;
        const float vx1 = (x1 >= 0 && x1 < Wl) ? 1.f : 0.f;
        const float vy0 = (y0 >= 0 && y0 < Wl) ? 1.f : 0.f;
        const float vy1 = (y1 >= 0 && y1 < Wl) ? 1.f : 0.f;

        const int xc0 = min(max(x0, 0), Wl - 1);
        const int xc1 = min(max(x1, 0), Wl - 1);
        const int yc0 = min(max(y0, 0), Wl - 1);
        const int yc1 = min(max(y1, 0), Wl - 1);

        const int row0 = st + yc0 * Wl;
        const int row1 = st + yc1 * Wl;
        const int hb   = h << 5;

        const int sidx = (lp * 9 + h) * 4;
        int4 a;
        a.x = ((row0 + xc0) << 8) + hb;
        a.y = ((row0 + xc1) << 8) + hb;
        a.z = ((row1 + xc0) << 8) + hb;
        a.w = ((row1 + xc1) << 8) + hb;
        *reinterpret_cast<int4*>(&s_addr[qi][sidx]) = a;

        float4 w;
        w.x = aw * (1.f - fx) * (1.f - fy) * vx0 * vy0;
        w.y = aw * fx * (1.f - fy) * vx1 * vy0;
        w.z = aw * (1.f - fx) * fy * vx0 * vy1;
        w.w = aw * fx * fy * vx1 * vy1;
        *reinterpret_cast<float4*>(&s_w[qi][sidx]) = w;
    }
    __syncthreads();

    // ---- MAIN: 16B gathers, corner-pairs split across wave halves ----
    const int c2 = t6 >> 5;            // 0: corners {00,01}, 1: {10,11}
    const int h  = (t6 >> 2) & 7;
    const int l2 = t6 & 3;
    const int d8 = l2 * 8;
    const ushort* __restrict__ vb = value + (q >= LQ_ ? (size_t)LEN_IN_ * 256 : 0) + d8;

    float acc[8];
#pragma unroll
    for (int j = 0; j < 8; ++j) acc[j] = 0.f;

#pragma unroll
    for (int pt = 0; pt < 16; ++pt) {
        const int base = (pt * 9 + h) * 4 + c2 * 2;
        const int2   a = *reinterpret_cast<const int2*>(&s_addr[qi][base]);
        const float2 w = *reinterpret_cast<const float2*>(&s_w[qi][base]);
        uint4 v0 = *reinterpret_cast<const uint4*>(vb + a.x);
        uint4 v1 = *reinterpret_cast<const uint4*>(vb + a.y);
        uint u;
#pragma unroll
        for (int j = 0; j < 4; ++j) {
            u = (&v0.x)[j];
            acc[2*j]   = fmaf(w.x, __builtin_bit_cast(float, u << 16), acc[2*j]);
            acc[2*j+1] = fmaf(w.x, __builtin_bit_cast(float, u), acc[2*j+1]);
        }
#pragma unroll
        for (int j = 0; j < 4; ++j) {
            u = (&v1.x)[j];
            acc[2*j]   = fmaf(w.y, __builtin_bit_cast(float, u << 16), acc[2*j]);
            acc[2*j+1] = fmaf(w.y, __builtin_bit_cast(float, u), acc[2*j+1]);
        }
    }

    // merge corner-pair halves (lane ^ 32 holds the other two corners)
#pragma unroll
    for (int j = 0; j < 8; ++j) acc[j] += __shfl_xor(acc[j], 32);

    if (c2 == 0) {
        union { ushort u16[8]; uint4 u4; } hh, ll;
#pragma unroll
        for (int j = 0; j < 8; ++j) {
            ushort hb16 = f2bf_hi(acc[j]);
            hh.u16[j] = hb16;
            ll.u16[j] = f2bf_hi(acc[j] - bf2f(hb16));
        }
        const size_t base = (size_t)q * 256 + (h << 5) + d8;
        *reinterpret_cast<uint4*>(midH + base) = hh.u4;
        *reinterpret_cast<uint4*>(midL + base) = ll.u4;
    }
}

// ---------------------------------------------------------------------------
extern "C" void kernel_launch(void* const* d_in, const int* in_sizes, int n_in,
                              void* d_out, int out_size, void* d_ws, size_t ws_size,
                              hipStream_t stream)
{
    const float* query  = (const float*)d_in[0];
    const float* refp   = (const float*)d_in[1];
    const float* inflat = (const float*)d_in[2];
    const float* W_off  = (const float*)d_in[5];
    const float* b_off  = (const float*)d_in[6];
    const float* W_attn = (const float*)d_in[7];
    const float* b_attn = (const float*)d_in[8];
    const float* W_val  = (const float*)d_in[9];
    const float* b_val  = (const float*)d_in[10];
    const float* W_out  = (const float*)d_in[11];
    const float* b_out  = (const float*)d_in[12];
    float* out = (float*)d_out;

    ushort* IH    = (ushort*)d_ws;            // inflat hi; later aliased as midH
    ushort* QH    = IH + APLANE;              // query hi;  later aliased as midL
    ushort* valbf = QH + APLANE;              // value bf16 (B, LEN_IN, 256)
    ushort* packB = valbf + APLANE;           // packed B (294912 ushorts)
    float*  offsb = (float*)(packB + PACKB_TOTAL);
    float*  attnb = offsb + APLANE;

    dim3 blk(256);

    hipLaunchKernelGGL(pack_kernel, dim3(6232), blk, 0, stream,
                       inflat, query, W_val, W_off, W_attn, W_out, IH, QH, packB);
    hipLaunchKernelGGL(gemm3_kernel, dim3(10, 96), blk, 0, stream,
                       IH, QH, packB, b_val, b_off, b_attn, valbf, offsb, attnb);
    hipLaunchKernelGGL(sampler_kernel, dim3(MROWS / 2), dim3(128), 0, stream,
                       valbf, offsb, attnb, refp, IH /*midH*/, QH /*midL*/);
    hipLaunchKernelGGL(gemm_out_kernel, dim3(4, 96), blk, 0, stream,
                       IH, QH, packB + OFF_UHI, packB + OFF_ULO, b_out, out);
}

// Round 9
// 94.971 us; speedup vs baseline: 2.0044x; 1.2262x over previous
//
#include <hip/hip_runtime.h>
#include <math.h>

#define B_    2
#define LQ_   12240
#define C_    256
#define NH_   8
#define NL_   4
#define NP_   4
#define LEN_IN_ 12240
#define MROWS (B_*LQ_)    // 24480
#define MF_   (MROWS/16)  // 1530 row fragments
#define KF_   8           // 256/32 k fragments
#define APLANE ((size_t)MROWS * C_)   // 6266880 elements
#define NBLK  383          // ceil(MROWS/64)

typedef __attribute__((ext_vector_type(8))) short short8v;   // 8 bf16
typedef __attribute__((ext_vector_type(4))) float f32x4;

__device__ __forceinline__ ushort f2bf_hi(float f) {
    uint u = __builtin_bit_cast(uint, f);
    uint r = (u + 0x7fffu + ((u >> 16) & 1u)) >> 16;
    return (ushort)r;
}
__device__ __forceinline__ float bf2f(ushort h) {
    uint u = ((uint)h) << 16;
    return __builtin_bit_cast(float, u);
}

// packed-B layout (ushort units):
//   [0,65536)        W_val  hi (nf 0..15)
//   [65536,131072)   W_off  hi (nf 0..15)
//   [131072,163840)  W_attn hi (nf 0..7)
//   [163840,229376)  W_out  hi (nf 0..15)
//   [229376,294912)  W_out  lo
#define U4_VAL  0
#define U4_OFF  8192
#define U4_ATT  16384
#define U4_UHI  20480
#define U4_ULO  28672
#define PACKB_TOTAL 294912

// ---------------------------------------------------------------------------
// Weights-only pack: B-fragment order, hi (+lo for W_out).
// frag index: ((nf*KF + kf)*64 + lane)*8 + j
// ---------------------------------------------------------------------------
__global__ __launch_bounds__(256) void pack_w_kernel(
    const float* __restrict__ Wv, const float* __restrict__ Wo,
    const float* __restrict__ Wa, const float* __restrict__ Wu,
    ushort* __restrict__ packB)
{
    int gid = blockIdx.x * 256 + threadIdx.x;
    if (gid >= 28672) return;
    const float* W; ushort* hi; ushort* lo = nullptr; int N, rel;
    if (gid < 8192)       { W = Wv; hi = packB;          N = 256; rel = gid; }
    else if (gid < 16384) { W = Wo; hi = packB + 65536;  N = 256; rel = gid - 8192; }
    else if (gid < 20480) { W = Wa; hi = packB + 131072; N = 128; rel = gid - 16384; }
    else { W = Wu; hi = packB + 163840; lo = packB + 229376; N = 256; rel = gid - 20480; }

    const int lane = rel & 63;
    const int kf   = (rel >> 6) & 7;
    const int nf   = rel >> 9;
    const int row0 = kf * 32 + (lane >> 4) * 8;
    const int col  = nf * 16 + (lane & 15);

    union { ushort u16[8]; uint4 u4; } ch, cl;
#pragma unroll
    for (int j = 0; j < 8; ++j) {
        float x = W[(size_t)(row0 + j) * N + col];
        ushort h = f2bf_hi(x);
        ch.u16[j] = h;
        cl.u16[j] = f2bf_hi(x - bf2f(h));
    }
    *reinterpret_cast<uint4*>(hi + (size_t)rel * 8) = ch.u4;
    if (lo) *reinterpret_cast<uint4*>(lo + (size_t)rel * 8) = cl.u4;
}

// ---------------------------------------------------------------------------
// Value GEMM: valbf(bf16) = inflat(f32) @ Wv + b_val.
// Block: 512 thr (8 waves), 64 rows (4 mf) x all 256 cols; wave = 2 nf.
// A: f32 -> bf16-hi converted into LDS, fragment-linear (conflict-free).
// B: fragment-packed from global (L2-resident). kf fully unrolled (MLP).
// ---------------------------------------------------------------------------
__global__ __launch_bounds__(512) void gemm_value_kernel(
    const float* __restrict__ A, const ushort* __restrict__ packB,
    const float* __restrict__ bias, ushort* __restrict__ Cg)
{
    const int t = threadIdx.x, lane = t & 63, wid = t >> 6;
    const int rowBase = blockIdx.x * 64;

    __shared__ ushort Als[2048 * 8];   // 32 KB

#pragma unroll
    for (int i = 0; i < 4; ++i) {
        int frag = i * 512 + t;
        int fl = frag & 63, kf = (frag >> 6) & 7, mf = frag >> 9;
        int row = min(rowBase + mf * 16 + (fl & 15), MROWS - 1);
        int k0 = kf * 32 + (fl >> 4) * 8;
        const float4* s = reinterpret_cast<const float4*>(A + (size_t)row * 256 + k0);
        float4 v0 = s[0], v1 = s[1];
        float vv[8] = { v0.x, v0.y, v0.z, v0.w, v1.x, v1.y, v1.z, v1.w };
        union { ushort u16[8]; uint4 u4; } hh;
#pragma unroll
        for (int j = 0; j < 8; ++j) hh.u16[j] = f2bf_hi(vv[j]);
        *reinterpret_cast<uint4*>(&Als[(size_t)frag * 8]) = hh.u4;
    }
    __syncthreads();

    const uint4* B4 = reinterpret_cast<const uint4*>(packB) + U4_VAL;
    const uint4* A4 = reinterpret_cast<const uint4*>(Als);
    const int wnf = wid * 2;

    f32x4 acc[4][2];
#pragma unroll
    for (int mi = 0; mi < 4; ++mi)
#pragma unroll
        for (int f = 0; f < 2; ++f) acc[mi][f] = (f32x4)0.0f;

#pragma unroll
    for (int kf = 0; kf < KF_; ++kf) {
        uint4 bh[2], ah[4];
#pragma unroll
        for (int f = 0; f < 2; ++f) bh[f] = B4[((wnf + f) * KF_ + kf) * 64 + lane];
#pragma unroll
        for (int mi = 0; mi < 4; ++mi) ah[mi] = A4[(mi * KF_ + kf) * 64 + lane];
#pragma unroll
        for (int mi = 0; mi < 4; ++mi) {
            short8v a = __builtin_bit_cast(short8v, ah[mi]);
#pragma unroll
            for (int f = 0; f < 2; ++f)
                acc[mi][f] = __builtin_amdgcn_mfma_f32_16x16x32_bf16(
                    a, __builtin_bit_cast(short8v, bh[f]), acc[mi][f], 0, 0, 0);
        }
    }

    const int colLane = lane & 15, rquad = lane >> 4;
#pragma unroll
    for (int f = 0; f < 2; ++f) {
        int col = (wnf + f) * 16 + colLane;
        float bv = bias[col];
#pragma unroll
        for (int mi = 0; mi < 4; ++mi)
#pragma unroll
            for (int e = 0; e < 4; ++e) {
                int row = rowBase + mi * 16 + rquad * 4 + e;
                if (row < MROWS) Cg[(size_t)row * 256 + col] = f2bf_hi(acc[mi][f][e] + bv);
            }
    }
}

// ---------------------------------------------------------------------------
// Query GEMM: offsb(f32,256) = query @ Wo + b_off ; attnb(f32,128) = query @ Wa.
// Block: 768 thr (12 waves): waves 0..7 -> offs (2 nf each), 8..11 -> attn.
// ---------------------------------------------------------------------------
__global__ __launch_bounds__(768) void gemm_query_kernel(
    const float* __restrict__ A, const ushort* __restrict__ packB,
    const float* __restrict__ b_off, const float* __restrict__ b_attn,
    float* __restrict__ offsb, float* __restrict__ attnb)
{
    const int t = threadIdx.x, lane = t & 63, wid = t >> 6;
    const int rowBase = blockIdx.x * 64;

    __shared__ ushort Als[2048 * 8];

#pragma unroll
    for (int i = 0; i < 3; ++i) {
        int frag = i * 768 + t;
        if (frag < 2048) {
            int fl = frag & 63, kf = (frag >> 6) & 7, mf = frag >> 9;
            int row = min(rowBase + mf * 16 + (fl & 15), MROWS - 1);
            int k0 = kf * 32 + (fl >> 4) * 8;
            const float4* s = reinterpret_cast<const float4*>(A + (size_t)row * 256 + k0);
            float4 v0 = s[0], v1 = s[1];
            float vv[8] = { v0.x, v0.y, v0.z, v0.w, v1.x, v1.y, v1.z, v1.w };
            union { ushort u16[8]; uint4 u4; } hh;
#pragma unroll
            for (int j = 0; j < 8; ++j) hh.u16[j] = f2bf_hi(vv[j]);
            *reinterpret_cast<uint4*>(&Als[(size_t)frag * 8]) = hh.u4;
        }
    }
    __syncthreads();

    const bool isAttn = wid >= 8;
    const int wnf = (isAttn ? (wid - 8) : wid) * 2;
    const uint4* B4 = reinterpret_cast<const uint4*>(packB) + (isAttn ? U4_ATT : U4_OFF);
    const uint4* A4 = reinterpret_cast<const uint4*>(Als);

    f32x4 acc[4][2];
#pragma unroll
    for (int mi = 0; mi < 4; ++mi)
#pragma unroll
        for (int f = 0; f < 2; ++f) acc[mi][f] = (f32x4)0.0f;

#pragma unroll
    for (int kf = 0; kf < KF_; ++kf) {
        uint4 bh[2], ah[4];
#pragma unroll
        for (int f = 0; f < 2; ++f) bh[f] = B4[((wnf + f) * KF_ + kf) * 64 + lane];
#pragma unroll
        for (int mi = 0; mi < 4; ++mi) ah[mi] = A4[(mi * KF_ + kf) * 64 + lane];
#pragma unroll
        for (int mi = 0; mi < 4; ++mi) {
            short8v a = __builtin_bit_cast(short8v, ah[mi]);
#pragma unroll
            for (int f = 0; f < 2; ++f)
                acc[mi][f] = __builtin_amdgcn_mfma_f32_16x16x32_bf16(
                    a, __builtin_bit_cast(short8v, bh[f]), acc[mi][f], 0, 0, 0);
        }
    }

    const int colLane = lane & 15, rquad = lane >> 4;
    const float* bias = isAttn ? b_attn : b_off;
    const int N = isAttn ? 128 : 256;
    float* outp = isAttn ? attnb : offsb;
#pragma unroll
    for (int f = 0; f < 2; ++f) {
        int col = (wnf + f) * 16 + colLane;
        float bv = bias[col];
#pragma unroll
        for (int mi = 0; mi < 4; ++mi)
#pragma unroll
            for (int e = 0; e < 4; ++e) {
                int row = rowBase + mi * 16 + rquad * 4 + e;
                if (row < MROWS) outp[(size_t)row * N + col] = acc[mi][f][e] + bv;
            }
    }
}

// ---------------------------------------------------------------------------
// Out GEMM (NPASS3): out(f32) = (midH+midL) @ (Wu_hi+Wu_lo) + b_out.
// Block: 512 thr, 64 rows x 256 cols; A hi+lo staged (64 KB LDS, frag copy).
// ---------------------------------------------------------------------------
__global__ __launch_bounds__(512) void gemm_out_kernel(
    const ushort* __restrict__ midH, const ushort* __restrict__ midL,
    const ushort* __restrict__ packB, const float* __restrict__ bias,
    float* __restrict__ Cg)
{
    const int t = threadIdx.x, lane = t & 63, wid = t >> 6;
    const int rowBase = blockIdx.x * 64;

    __shared__ ushort Ahs[2048 * 8];
    __shared__ ushort Alo[2048 * 8];

    const uint4* H4 = reinterpret_cast<const uint4*>(midH);
    const uint4* L4 = reinterpret_cast<const uint4*>(midL);
#pragma unroll
    for (int i = 0; i < 4; ++i) {
        int frag = i * 512 + t;
        int fl = frag & 63, kf = (frag >> 6) & 7, mf = frag >> 9;
        int row = min(rowBase + mf * 16 + (fl & 15), MROWS - 1);
        int kq = kf * 4 + (fl >> 4);      // uint4 index within row (32 per row)
        *reinterpret_cast<uint4*>(&Ahs[(size_t)frag * 8]) = H4[(size_t)row * 32 + kq];
        *reinterpret_cast<uint4*>(&Alo[(size_t)frag * 8]) = L4[(size_t)row * 32 + kq];
    }
    __syncthreads();

    const uint4* BH4 = reinterpret_cast<const uint4*>(packB) + U4_UHI;
    const uint4* BL4 = reinterpret_cast<const uint4*>(packB) + U4_ULO;
    const uint4* AH4 = reinterpret_cast<const uint4*>(Ahs);
    const uint4* AL4 = reinterpret_cast<const uint4*>(Alo);
    const int wnf = wid * 2;

    f32x4 acc[4][2];
#pragma unroll
    for (int mi = 0; mi < 4; ++mi)
#pragma unroll
        for (int f = 0; f < 2; ++f) acc[mi][f] = (f32x4)0.0f;

#pragma unroll 2
    for (int kf = 0; kf < KF_; ++kf) {
        uint4 bh[2], bl[2], ah[4], al[4];
#pragma unroll
        for (int f = 0; f < 2; ++f) {
            bh[f] = BH4[((wnf + f) * KF_ + kf) * 64 + lane];
            bl[f] = BL4[((wnf + f) * KF_ + kf) * 64 + lane];
        }
#pragma unroll
        for (int mi = 0; mi < 4; ++mi) {
            ah[mi] = AH4[(mi * KF_ + kf) * 64 + lane];
            al[mi] = AL4[(mi * KF_ + kf) * 64 + lane];
        }
#pragma unroll
        for (int mi = 0; mi < 4; ++mi) {
            short8v a  = __builtin_bit_cast(short8v, ah[mi]);
            short8v av = __builtin_bit_cast(short8v, al[mi]);
#pragma unroll
            for (int f = 0; f < 2; ++f) {
                short8v b = __builtin_bit_cast(short8v, bh[f]);
                acc[mi][f] = __builtin_amdgcn_mfma_f32_16x16x32_bf16(a, b, acc[mi][f], 0, 0, 0);
                acc[mi][f] = __builtin_amdgcn_mfma_f32_16x16x32_bf16(
                    a, __builtin_bit_cast(short8v, bl[f]), acc[mi][f], 0, 0, 0);
                acc[mi][f] = __builtin_amdgcn_mfma_f32_16x16x32_bf16(av, b, acc[mi][f], 0, 0, 0);
            }
        }
    }

    const int colLane = lane & 15, rquad = lane >> 4;
#pragma unroll
    for (int f = 0; f < 2; ++f) {
        int col = (wnf + f) * 16 + colLane;
        float bv = bias[col];
#pragma unroll
        for (int mi = 0; mi < 4; ++mi)
#pragma unroll
            for (int e = 0; e < 4; ++e) {
                int row = rowBase + mi * 16 + rquad * 4 + e;
                if (row < MROWS) Cg[(size_t)row * 256 + col] = acc[mi][f][e] + bv;
            }
    }
}

// ---------------------------------------------------------------------------
// Fused softmax + bilinear sampling on bf16 value (R7 structure).
// ---------------------------------------------------------------------------
__global__ __launch_bounds__(128) void sampler_kernel(
    const ushort* __restrict__ value,  // (B, LEN_IN, 256) bf16
    const float* __restrict__ offs,    // (B*LQ, 256)
    const float* __restrict__ attnw,   // (B*LQ, 128)
    const float* __restrict__ refp,    // (B, LQ, NL, 2)
    ushort* __restrict__ midH, ushort* __restrict__ midL)
{
    const int t  = threadIdx.x;
    const int qi = t >> 6;
    const int t6 = t & 63;
    const int q  = blockIdx.x * 2 + qi;

    __shared__ float s_ref[2][8];
    __shared__ int   s_addr[2][576];
    __shared__ float s_w[2][576];

    if (t < 16) s_ref[t >> 3][t & 7] = refp[(size_t)(blockIdx.x * 2 + (t >> 3)) * 8 + (t & 7)];
    __syncthreads();

#pragma unroll
    for (int batch = 0; batch < 2; ++batch) {
        const int p  = t6 + batch * 64;
        const int h  = p >> 4;
        const int lp = p & 15;
        const int l  = lp >> 2;

        float raw = attnw[(size_t)q * 128 + p];
        float mx = raw;
#pragma unroll
        for (int m = 8; m >= 1; m >>= 1) mx = fmaxf(mx, __shfl_xor(mx, m, 16));
        float e = __expf(raw - mx);
        float sum = e;
#pragma unroll
        for (int m = 8; m >= 1; m >>= 1) sum += __shfl_xor(sum, m, 16);
        const float aw = e / sum;

        const float2 o = reinterpret_cast<const float2*>(offs)[(size_t)q * 128 + p];
        const float rx = s_ref[qi][l * 2 + 0];
        const float ry = s_ref[qi][l * 2 + 1];

        const int   Wl = 96 >> l;
        const int   st = 12288 - (12288 >> (2 * l));
        const float fW = (float)Wl;

        const float x = fmaf(rx, fW, o.x) - 0.5f;
        const float y = fmaf(ry, fW, o.y) - 0.5f;
        const float x0f = floorf(x), y0f = floorf(y);
        const float fx = x - x0f, fy = y - y0f;
        const int x0 = (int)x0f, y0 = (int)y0f;
        const int x1 = x0 + 1,   y1 = y0 + 1;

        const float vx0 = (x0 >= 0 && x0 < Wl) ? 1.f : 0.f;
        const float vx1 = (x1 >= 0 && x1 < Wl) ? 1.f : 0.f;
        const float vy0 = (y0 >= 0 && y0 < Wl) ? 1.f : 0.f;
        const float vy1 = (y1 >= 0 && y1 < Wl) ? 1.f : 0.f;

        const int xc0 = min(max(x0, 0), Wl - 1);
        const int xc1 = min(max(x1, 0), Wl - 1);
        const int yc0 = min(max(y0, 0), Wl - 1);
        const int yc1 = min(max(y1, 0), Wl - 1);

        const int row0 = st + yc0 * Wl;
        const int row1 = st + yc1 * Wl;
        const int hb   = h << 5;

        const int sidx = (lp * 9 + h) * 4;
        int4 a;
        a.x = ((row0 + xc0) << 8) + hb;
        a.y = ((row0 + xc1) << 8) + hb;
        a.z = ((row1 + xc0) << 8) + hb;
        a.w = ((row1 + xc1) << 8) + hb;
        *reinterpret_cast<int4*>(&s_addr[qi][sidx]) = a;

        float4 w;
        w.x = aw * (1.f - fx) * (1.f - fy) * vx0 * vy0;
        w.y = aw * fx * (1.f - fy) * vx1 * vy0;
        w.z = aw * (1.f - fx) * fy * vx0 * vy1;
        w.w = aw * fx * fy * vx1 * vy1;
        *reinterpret_cast<float4*>(&s_w[qi][sidx]) = w;
    }
    __syncthreads();

    // ---- MAIN: 16B gathers, corner-pairs split across wave halves ----
    const int c2 = t6 >> 5;
    const int h  = (t6 >> 2) & 7;
    const int l2 = t6 & 3;
    const int d8 = l2 * 8;
    const ushort* __restrict__ vb = value + (q >= LQ_ ? (size_t)LEN_IN_ * 256 : 0) + d8;

    float acc[8];
#pragma unroll
    for (int j = 0; j < 8; ++j) acc[j] = 0.f;

#pragma unroll
    for (int pt = 0; pt < 16; ++pt) {
        const int base = (pt * 9 + h) * 4 + c2 * 2;
        const int2   a = *reinterpret_cast<const int2*>(&s_addr[qi][base]);
        const float2 w = *reinterpret_cast<const float2*>(&s_w[qi][base]);
        uint4 v0 = *reinterpret_cast<const uint4*>(vb + a.x);
        uint4 v1 = *reinterpret_cast<const uint4*>(vb + a.y);
        uint u;
#pragma unroll
        for (int j = 0; j < 4; ++j) {
            u = (&v0.x)[j];
            acc[2*j]   = fmaf(w.x, __builtin_bit_cast(float, u << 16), acc[2*j]);
            acc[2*j+1] = fmaf(w.x, __builtin_bit_cast(float, u), acc[2*j+1]);
        }
#pragma unroll
        for (int j = 0; j < 4; ++j) {
            u = (&v1.x)[j];
            acc[2*j]   = fmaf(w.y, __builtin_bit_cast(float, u << 16), acc[2*j]);
            acc[2*j+1] = fmaf(w.y, __builtin_bit_cast(float, u), acc[2*j+1]);
        }
    }

#pragma unroll
    for (int j = 0; j < 8; ++j) acc[j] += __shfl_xor(acc[j], 32);

    if (c2 == 0) {
        union { ushort u16[8]; uint4 u4; } hh, ll;
#pragma unroll
        for (int j = 0; j < 8; ++j) {
            ushort hb16 = f2bf_hi(acc[j]);
            hh.u16[j] = hb16;
            ll.u16[j] = f2bf_hi(acc[j] - bf2f(hb16));
        }
        const size_t base = (size_t)q * 256 + (h << 5) + d8;
        *reinterpret_cast<uint4*>(midH + base) = hh.u4;
        *reinterpret_cast<uint4*>(midL + base) = ll.u4;
    }
}

// ---------------------------------------------------------------------------
extern "C" void kernel_launch(void* const* d_in, const int* in_sizes, int n_in,
                              void* d_out, int out_size, void* d_ws, size_t ws_size,
                              hipStream_t stream)
{
    const float* query  = (const float*)d_in[0];
    const float* refp   = (const float*)d_in[1];
    const float* inflat = (const float*)d_in[2];
    const float* W_off  = (const float*)d_in[5];
    const float* b_off  = (const float*)d_in[6];
    const float* W_attn = (const float*)d_in[7];
    const float* b_attn = (const float*)d_in[8];
    const float* W_val  = (const float*)d_in[9];
    const float* b_val  = (const float*)d_in[10];
    const float* W_out  = (const float*)d_in[11];
    const float* b_out  = (const float*)d_in[12];
    float* out = (float*)d_out;

    ushort* midH  = (ushort*)d_ws;
    ushort* midL  = midH + APLANE;
    ushort* valbf = midL + APLANE;
    ushort* packB = valbf + APLANE;
    float*  offsb = (float*)(packB + PACKB_TOTAL);
    float*  attnb = offsb + APLANE;

    hipLaunchKernelGGL(pack_w_kernel, dim3(112), dim3(256), 0, stream,
                       W_val, W_off, W_attn, W_out, packB);
    hipLaunchKernelGGL(gemm_value_kernel, dim3(NBLK), dim3(512), 0, stream,
                       inflat, packB, b_val, valbf);
    hipLaunchKernelGGL(gemm_query_kernel, dim3(NBLK), dim3(768), 0, stream,
                       query, packB, b_off, b_attn, offsb, attnb);
    hipLaunchKernelGGL(sampler_kernel, dim3(MROWS / 2), dim3(128), 0, stream,
                       valbf, offsb, attnb, refp, midH, midL);
    hipLaunchKernelGGL(gemm_out_kernel, dim3(NBLK), dim3(512), 0, stream,
                       midH, midL, packB, b_out, out);
}

// Round 10
// 89.204 us; speedup vs baseline: 2.1340x; 1.0646x over previous
//
#include <hip/hip_runtime.h>
#include <math.h>

#define B_    2
#define LQ_   12240
#define C_    256
#define NH_   8
#define NL_   4
#define NP_   4
#define LEN_IN_ 12240
#define MROWS (B_*LQ_)    // 24480
#define MF_   (MROWS/16)  // 1530
#define KF_   8           // 256/32
#define APLANE ((size_t)MROWS * C_)
#define NBLK  383          // ceil(MROWS/64)

typedef __attribute__((ext_vector_type(8))) short short8v;
typedef __attribute__((ext_vector_type(4))) float f32x4;
typedef __attribute__((ext_vector_type(2))) float f32x2;
typedef __attribute__((ext_vector_type(2))) uint  u32x2;

__device__ __forceinline__ ushort f2bf_hi(float f) {
    uint u = __builtin_bit_cast(uint, f);
    uint r = (u + 0x7fffu + ((u >> 16) & 1u)) >> 16;
    return (ushort)r;
}
__device__ __forceinline__ float bf2f(ushort h) {
    uint u = ((uint)h) << 16;
    return __builtin_bit_cast(float, u);
}

// packed-B layout (uint4 units):
#define U4_VAL  0
#define U4_OFF  8192
#define U4_ATT  16384
#define U4_UHI  20480
#define U4_ULO  28672
#define PACKB_TOTAL 294912   // ushorts

// ---------------------------------------------------------------------------
// Weights-only pack: B-fragment order, hi (+lo for W_out).
// ---------------------------------------------------------------------------
__global__ __launch_bounds__(256) void pack_w_kernel(
    const float* __restrict__ Wv, const float* __restrict__ Wo,
    const float* __restrict__ Wa, const float* __restrict__ Wu,
    ushort* __restrict__ packB)
{
    int gid = blockIdx.x * 256 + threadIdx.x;
    if (gid >= 28672) return;
    const float* W; ushort* hi; ushort* lo = nullptr; int N, rel;
    if (gid < 8192)       { W = Wv; hi = packB;          N = 256; rel = gid; }
    else if (gid < 16384) { W = Wo; hi = packB + 65536;  N = 256; rel = gid - 8192; }
    else if (gid < 20480) { W = Wa; hi = packB + 131072; N = 128; rel = gid - 16384; }
    else { W = Wu; hi = packB + 163840; lo = packB + 229376; N = 256; rel = gid - 20480; }

    const int lane = rel & 63;
    const int kf   = (rel >> 6) & 7;
    const int nf   = rel >> 9;
    const int row0 = kf * 32 + (lane >> 4) * 8;
    const int col  = nf * 16 + (lane & 15);

    union { ushort u16[8]; uint4 u4; } ch, cl;
#pragma unroll
    for (int j = 0; j < 8; ++j) {
        float x = W[(size_t)(row0 + j) * N + col];
        ushort h = f2bf_hi(x);
        ch.u16[j] = h;
        cl.u16[j] = f2bf_hi(x - bf2f(h));
    }
    *reinterpret_cast<uint4*>(hi + (size_t)rel * 8) = ch.u4;
    if (lo) *reinterpret_cast<uint4*>(lo + (size_t)rel * 8) = cl.u4;
}

// ---------------------------------------------------------------------------
// Merged value+query GEMM.  blockIdx.y==0: valbf(bf16)=inflat@Wv+b_val.
// blockIdx.y==1: offsb(f32)=query@Wo+b_off AND attnb(f32)=softmax(query@Wa+b_attn).
// 512 thr (8 waves), 64 rows/block, A f32->bf16-hi staged fragment-linear in
// LDS; B fragments streamed from L2.  Query wave w: offs nf {2w,2w+1} + attn
// head w; per-head softmax via 16-lane shfl groups (head == one 16-col frag).
// ---------------------------------------------------------------------------
__global__ __launch_bounds__(512) void gemm_vq_kernel(
    const float* __restrict__ inflat, const float* __restrict__ query,
    const ushort* __restrict__ packB,
    const float* __restrict__ b_val, const float* __restrict__ b_off,
    const float* __restrict__ b_attn,
    ushort* __restrict__ valbf, float* __restrict__ offsb, float* __restrict__ attnb)
{
    const int t = threadIdx.x, lane = t & 63, wid = t >> 6;
    const int rowBase = blockIdx.x * 64;
    const bool isVal = (blockIdx.y == 0);
    const float* __restrict__ A = isVal ? inflat : query;

    __shared__ ushort Als[2048 * 8];   // 32 KB

#pragma unroll
    for (int i = 0; i < 4; ++i) {
        int frag = i * 512 + t;
        int fl = frag & 63, kf = (frag >> 6) & 7, mf = frag >> 9;
        int row = min(rowBase + mf * 16 + (fl & 15), MROWS - 1);
        int k0 = kf * 32 + (fl >> 4) * 8;
        const float4* s = reinterpret_cast<const float4*>(A + (size_t)row * 256 + k0);
        float4 v0 = s[0], v1 = s[1];
        float vv[8] = { v0.x, v0.y, v0.z, v0.w, v1.x, v1.y, v1.z, v1.w };
        union { ushort u16[8]; uint4 u4; } hh;
#pragma unroll
        for (int j = 0; j < 8; ++j) hh.u16[j] = f2bf_hi(vv[j]);
        *reinterpret_cast<uint4*>(&Als[(size_t)frag * 8]) = hh.u4;
    }
    __syncthreads();

    const uint4* A4 = reinterpret_cast<const uint4*>(Als);
    const int colLane = lane & 15, rquad = lane >> 4;
    const int wnf = wid * 2;

    if (isVal) {
        const uint4* B4 = reinterpret_cast<const uint4*>(packB) + U4_VAL;
        f32x4 acc[4][2];
#pragma unroll
        for (int mi = 0; mi < 4; ++mi)
#pragma unroll
            for (int f = 0; f < 2; ++f) acc[mi][f] = (f32x4)0.0f;

#pragma unroll
        for (int kf = 0; kf < KF_; ++kf) {
            uint4 bh[2], ah[4];
#pragma unroll
            for (int f = 0; f < 2; ++f) bh[f] = B4[((wnf + f) * KF_ + kf) * 64 + lane];
#pragma unroll
            for (int mi = 0; mi < 4; ++mi) ah[mi] = A4[(mi * KF_ + kf) * 64 + lane];
#pragma unroll
            for (int mi = 0; mi < 4; ++mi) {
                short8v a = __builtin_bit_cast(short8v, ah[mi]);
#pragma unroll
                for (int f = 0; f < 2; ++f)
                    acc[mi][f] = __builtin_amdgcn_mfma_f32_16x16x32_bf16(
                        a, __builtin_bit_cast(short8v, bh[f]), acc[mi][f], 0, 0, 0);
            }
        }
#pragma unroll
        for (int f = 0; f < 2; ++f) {
            int col = (wnf + f) * 16 + colLane;
            float bv = b_val[col];
#pragma unroll
            for (int mi = 0; mi < 4; ++mi)
#pragma unroll
                for (int e = 0; e < 4; ++e) {
                    int row = rowBase + mi * 16 + rquad * 4 + e;
                    if (row < MROWS) valbf[(size_t)row * 256 + col] = f2bf_hi(acc[mi][f][e] + bv);
                }
        }
    } else {
        const uint4* BO = reinterpret_cast<const uint4*>(packB) + U4_OFF;
        const uint4* BA = reinterpret_cast<const uint4*>(packB) + U4_ATT;
        f32x4 acc[4][3];
#pragma unroll
        for (int mi = 0; mi < 4; ++mi)
#pragma unroll
            for (int f = 0; f < 3; ++f) acc[mi][f] = (f32x4)0.0f;

#pragma unroll
        for (int kf = 0; kf < KF_; ++kf) {
            uint4 bh[3], ah[4];
#pragma unroll
            for (int f = 0; f < 2; ++f) bh[f] = BO[((wnf + f) * KF_ + kf) * 64 + lane];
            bh[2] = BA[(wid * KF_ + kf) * 64 + lane];
#pragma unroll
            for (int mi = 0; mi < 4; ++mi) ah[mi] = A4[(mi * KF_ + kf) * 64 + lane];
#pragma unroll
            for (int mi = 0; mi < 4; ++mi) {
                short8v a = __builtin_bit_cast(short8v, ah[mi]);
#pragma unroll
                for (int f = 0; f < 3; ++f)
                    acc[mi][f] = __builtin_amdgcn_mfma_f32_16x16x32_bf16(
                        a, __builtin_bit_cast(short8v, bh[f]), acc[mi][f], 0, 0, 0);
            }
        }
        // offs epilogue
#pragma unroll
        for (int f = 0; f < 2; ++f) {
            int col = (wnf + f) * 16 + colLane;
            float bv = b_off[col];
#pragma unroll
            for (int mi = 0; mi < 4; ++mi)
#pragma unroll
                for (int e = 0; e < 4; ++e) {
                    int row = rowBase + mi * 16 + rquad * 4 + e;
                    if (row < MROWS) offsb[(size_t)row * 256 + col] = acc[mi][f][e] + bv;
                }
        }
        // attn epilogue with fused softmax (head = wid; 16 cols in 16-lane group)
        {
            int col = wid * 16 + colLane;
            float bv = b_attn[col];
#pragma unroll
            for (int mi = 0; mi < 4; ++mi)
#pragma unroll
                for (int e = 0; e < 4; ++e) {
                    float v = acc[mi][2][e] + bv;
                    float mx = v;
#pragma unroll
                    for (int m = 8; m >= 1; m >>= 1) mx = fmaxf(mx, __shfl_xor(mx, m, 16));
                    float ex = __expf(v - mx);
                    float s = ex;
#pragma unroll
                    for (int m = 8; m >= 1; m >>= 1) s += __shfl_xor(s, m, 16);
                    int row = rowBase + mi * 16 + rquad * 4 + e;
                    if (row < MROWS) attnb[(size_t)row * 128 + col] = ex / s;
                }
        }
    }
}

// ---------------------------------------------------------------------------
// Out GEMM: out(f32) = midH(bf16) @ (Wu_hi + Wu_lo) + b_out.  (A-lo dropped:
// adds ~2^-9-rel error, removes midL entirely.)
// ---------------------------------------------------------------------------
__global__ __launch_bounds__(512) void gemm_out_kernel(
    const ushort* __restrict__ midH, const ushort* __restrict__ packB,
    const float* __restrict__ bias, float* __restrict__ Cg)
{
    const int t = threadIdx.x, lane = t & 63, wid = t >> 6;
    const int rowBase = blockIdx.x * 64;

    __shared__ ushort Ahs[2048 * 8];

    const uint4* H4 = reinterpret_cast<const uint4*>(midH);
#pragma unroll
    for (int i = 0; i < 4; ++i) {
        int frag = i * 512 + t;
        int fl = frag & 63, kf = (frag >> 6) & 7, mf = frag >> 9;
        int row = min(rowBase + mf * 16 + (fl & 15), MROWS - 1);
        int kq = kf * 4 + (fl >> 4);
        *reinterpret_cast<uint4*>(&Ahs[(size_t)frag * 8]) = H4[(size_t)row * 32 + kq];
    }
    __syncthreads();

    const uint4* BH4 = reinterpret_cast<const uint4*>(packB) + U4_UHI;
    const uint4* BL4 = reinterpret_cast<const uint4*>(packB) + U4_ULO;
    const uint4* A4 = reinterpret_cast<const uint4*>(Ahs);
    const int wnf = wid * 2;

    f32x4 acc[4][2];
#pragma unroll
    for (int mi = 0; mi < 4; ++mi)
#pragma unroll
        for (int f = 0; f < 2; ++f) acc[mi][f] = (f32x4)0.0f;

#pragma unroll
    for (int kf = 0; kf < KF_; ++kf) {
        uint4 bh[2], bl[2], ah[4];
#pragma unroll
        for (int f = 0; f < 2; ++f) {
            bh[f] = BH4[((wnf + f) * KF_ + kf) * 64 + lane];
            bl[f] = BL4[((wnf + f) * KF_ + kf) * 64 + lane];
        }
#pragma unroll
        for (int mi = 0; mi < 4; ++mi) ah[mi] = A4[(mi * KF_ + kf) * 64 + lane];
#pragma unroll
        for (int mi = 0; mi < 4; ++mi) {
            short8v a = __builtin_bit_cast(short8v, ah[mi]);
#pragma unroll
            for (int f = 0; f < 2; ++f) {
                acc[mi][f] = __builtin_amdgcn_mfma_f32_16x16x32_bf16(
                    a, __builtin_bit_cast(short8v, bh[f]), acc[mi][f], 0, 0, 0);
                acc[mi][f] = __builtin_amdgcn_mfma_f32_16x16x32_bf16(
                    a, __builtin_bit_cast(short8v, bl[f]), acc[mi][f], 0, 0, 0);
            }
        }
    }

    const int colLane = lane & 15, rquad = lane >> 4;
#pragma unroll
    for (int f = 0; f < 2; ++f) {
        int col = (wnf + f) * 16 + colLane;
        float bv = bias[col];
#pragma unroll
        for (int mi = 0; mi < 4; ++mi)
#pragma unroll
            for (int e = 0; e < 4; ++e) {
                int row = rowBase + mi * 16 + rquad * 4 + e;
                if (row < MROWS) Cg[(size_t)row * 256 + col] = acc[mi][f][e] + bv;
            }
    }
}

// ---------------------------------------------------------------------------
// Sampler: softmax pre-applied (attnb holds weights).  Main loop uses packed
// f32 FMA (float2 -> v_pk_fma_f32) and free-hi bf16 decode.  Writes midH only.
// ---------------------------------------------------------------------------
__global__ __launch_bounds__(128) void sampler_kernel(
    const ushort* __restrict__ value,
    const float* __restrict__ offs,
    const float* __restrict__ attnw,   // softmaxed weights
    const float* __restrict__ refp,
    ushort* __restrict__ midH)
{
    const int t  = threadIdx.x;
    const int qi = t >> 6;
    const int t6 = t & 63;
    const int q  = blockIdx.x * 2 + qi;

    __shared__ float s_ref[2][8];
    __shared__ int   s_addr[2][576];
    __shared__ float s_w[2][576];

    if (t < 16) s_ref[t >> 3][t & 7] = refp[(size_t)(blockIdx.x * 2 + (t >> 3)) * 8 + (t & 7)];
    __syncthreads();

#pragma unroll
    for (int batch = 0; batch < 2; ++batch) {
        const int p  = t6 + batch * 64;
        const int h  = p >> 4;
        const int lp = p & 15;
        const int l  = lp >> 2;

        const float aw = attnw[(size_t)q * 128 + p];
        const float2 o = reinterpret_cast<const float2*>(offs)[(size_t)q * 128 + p];
        const float rx = s_ref[qi][l * 2 + 0];
        const float ry = s_ref[qi][l * 2 + 1];

        const int   Wl = 96 >> l;
        const int   st = 12288 - (12288 >> (2 * l));
        const float fW = (float)Wl;

        const float x = fmaf(rx, fW, o.x) - 0.5f;
        const float y = fmaf(ry, fW, o.y) - 0.5f;
        const float x0f = floorf(x), y0f = floorf(y);
        const float fx = x - x0f, fy = y - y0f;
        const int x0 = (int)x0f, y0 = (int)y0f;
        const int x1 = x0 + 1,   y1 = y0 + 1;

        const float vx0 = (x0 >= 0 && x0 < Wl) ? 1.f : 0.f;
        const float vx1 = (x1 >= 0 && x1 < Wl) ? 1.f : 0.f;
        const float vy0 = (y0 >= 0 && y0 < Wl) ? 1.f : 0.f;
        const float vy1 = (y1 >= 0 && y1 < Wl) ? 1.f : 0.f;

        const int xc0 = min(max(x0, 0), Wl - 1);
        const int xc1 = min(max(x1, 0), Wl - 1);
        const int yc0 = min(max(y0, 0), Wl - 1);
        const int yc1 = min(max(y1, 0), Wl - 1);

        const int row0 = st + yc0 * Wl;
        const int row1 = st + yc1 * Wl;
        const int hb   = h << 5;

        const int sidx = (lp * 9 + h) * 4;
        int4 a;
        a.x = ((row0 + xc0) << 8) + hb;
        a.y = ((row0 + xc1) << 8) + hb;
        a.z = ((row1 + xc0) << 8) + hb;
        a.w = ((row1 + xc1) << 8) + hb;
        *reinterpret_cast<int4*>(&s_addr[qi][sidx]) = a;

        float4 w;
        w.x = aw * (1.f - fx) * (1.f - fy) * vx0 * vy0;
        w.y = aw * fx * (1.f - fy) * vx1 * vy0;
        w.z = aw * (1.f - fx) * fy * vx0 * vy1;
        w.w = aw * fx * fy * vx1 * vy1;
        *reinterpret_cast<float4*>(&s_w[qi][sidx]) = w;
    }
    __syncthreads();

    const int c2 = t6 >> 5;
    const int h  = (t6 >> 2) & 7;
    const int l2 = t6 & 3;
    const int d8 = l2 * 8;
    const ushort* __restrict__ vb = value + (q >= LQ_ ? (size_t)LEN_IN_ * 256 : 0) + d8;

    f32x2 aLo = (f32x2)0.f, aHi = (f32x2)0.f, bLo = (f32x2)0.f, bHi = (f32x2)0.f;

#pragma unroll
    for (int pt = 0; pt < 16; ++pt) {
        const int base = (pt * 9 + h) * 4 + c2 * 2;
        const int2   a = *reinterpret_cast<const int2*>(&s_addr[qi][base]);
        const float2 w = *reinterpret_cast<const float2*>(&s_w[qi][base]);
        uint4 v0 = *reinterpret_cast<const uint4*>(vb + a.x);
        uint4 v1 = *reinterpret_cast<const uint4*>(vb + a.y);
        f32x2 w0; w0.x = w.x; w0.y = w.x;
        f32x2 w1; w1.x = w.y; w1.y = w.y;

        u32x2 h01; h01.x = v0.x; h01.y = v0.y;
        u32x2 h23; h23.x = v0.z; h23.y = v0.w;
        u32x2 l01 = h01 << 16, l23 = h23 << 16;
        aHi = __builtin_elementwise_fma(__builtin_bit_cast(f32x2, h01), w0, aHi);
        aLo = __builtin_elementwise_fma(__builtin_bit_cast(f32x2, l01), w0, aLo);
        bHi = __builtin_elementwise_fma(__builtin_bit_cast(f32x2, h23), w0, bHi);
        bLo = __builtin_elementwise_fma(__builtin_bit_cast(f32x2, l23), w0, bLo);

        u32x2 g01; g01.x = v1.x; g01.y = v1.y;
        u32x2 g23; g23.x = v1.z; g23.y = v1.w;
        u32x2 m01 = g01 << 16, m23 = g23 << 16;
        aHi = __builtin_elementwise_fma(__builtin_bit_cast(f32x2, g01), w1, aHi);
        aLo = __builtin_elementwise_fma(__builtin_bit_cast(f32x2, m01), w1, aLo);
        bHi = __builtin_elementwise_fma(__builtin_bit_cast(f32x2, g23), w1, bHi);
        bLo = __builtin_elementwise_fma(__builtin_bit_cast(f32x2, m23), w1, bLo);
    }

    float r[8] = { aLo.x, aHi.x, aLo.y, aHi.y, bLo.x, bHi.x, bLo.y, bHi.y };
#pragma unroll
    for (int j = 0; j < 8; ++j) r[j] += __shfl_xor(r[j], 32);

    if (c2 == 0) {
        union { ushort u16[8]; uint4 u4; } hh;
#pragma unroll
        for (int j = 0; j < 8; ++j) hh.u16[j] = f2bf_hi(r[j]);
        *reinterpret_cast<uint4*>(midH + (size_t)q * 256 + (h << 5) + d8) = hh.u4;
    }
}

// ---------------------------------------------------------------------------
extern "C" void kernel_launch(void* const* d_in, const int* in_sizes, int n_in,
                              void* d_out, int out_size, void* d_ws, size_t ws_size,
                              hipStream_t stream)
{
    const float* query  = (const float*)d_in[0];
    const float* refp   = (const float*)d_in[1];
    const float* inflat = (const float*)d_in[2];
    const float* W_off  = (const float*)d_in[5];
    const float* b_off  = (const float*)d_in[6];
    const float* W_attn = (const float*)d_in[7];
    const float* b_attn = (const float*)d_in[8];
    const float* W_val  = (const float*)d_in[9];
    const float* b_val  = (const float*)d_in[10];
    const float* W_out  = (const float*)d_in[11];
    const float* b_out  = (const float*)d_in[12];
    float* out = (float*)d_out;

    ushort* midH  = (ushort*)d_ws;
    ushort* valbf = midH + APLANE;
    ushort* packB = valbf + APLANE;
    float*  offsb = (float*)(packB + PACKB_TOTAL);
    float*  attnb = offsb + APLANE;

    hipLaunchKernelGGL(pack_w_kernel, dim3(112), dim3(256), 0, stream,
                       W_val, W_off, W_attn, W_out, packB);
    hipLaunchKernelGGL(gemm_vq_kernel, dim3(NBLK, 2), dim3(512), 0, stream,
                       inflat, query, packB, b_val, b_off, b_attn,
                       valbf, offsb, attnb);
    hipLaunchKernelGGL(sampler_kernel, dim3(MROWS / 2), dim3(128), 0, stream,
                       valbf, offsb, attnb, refp, midH);
    hipLaunchKernelGGL(gemm_out_kernel, dim3(NBLK), dim3(512), 0, stream,
                       midH, packB, b_out, out);
}